// Round 10
// baseline (773.609 us; speedup 1.0000x reference)
//
#include <hip/hip_runtime.h>
#include <math.h>

#define NEG_SLOPE 0.2f

typedef __attribute__((ext_vector_type(8))) short short8;
typedef __attribute__((ext_vector_type(4))) float float4v;

__device__ __forceinline__ void atomAddF(float* p, float v) {
    unsafeAtomicAdd(p, v);   // HW global_atomic_add_f32 on gfx950
}
__device__ __forceinline__ unsigned short f2bf(float f) {
    unsigned u = __float_as_uint(f);
    unsigned r = (u + 0x7FFFu + ((u >> 16) & 1u)) >> 16;   // RNE
    return (unsigned short)r;
}
__device__ __forceinline__ float bf2f(unsigned short b) {
    return __uint_as_float((unsigned)b << 16);
}

// ================= CSR build (counting sort by dst) =================
__global__ void hist_kernel(const int* __restrict__ dst, int* __restrict__ cnt, int E) {
    int e = blockIdx.x * blockDim.x + threadIdx.x;
    if (e < E) atomicAdd(&cnt[dst[e]], 1);
}

__global__ void scan1_kernel(const int* __restrict__ cnt, int* __restrict__ incl,
                             int* __restrict__ bsum, int n) {
    __shared__ int s[256];
    int t = threadIdx.x, i = blockIdx.x * 256 + t;
    int v = (i < n) ? cnt[i] : 0;
    s[t] = v; __syncthreads();
    for (int o = 1; o < 256; o <<= 1) {
        int u = (t >= o) ? s[t - o] : 0;
        __syncthreads(); s[t] += u; __syncthreads();
    }
    if (i < n) incl[i] = s[t];
    if (t == 255) bsum[blockIdx.x] = s[255];
}

__global__ void scan2_kernel(int* __restrict__ bsum, int nb) {
    __shared__ int s[512];
    int t = threadIdx.x;
    int v = (t < nb) ? bsum[t] : 0;
    s[t] = v; __syncthreads();
    for (int o = 1; o < 512; o <<= 1) {
        int u = (t >= o) ? s[t - o] : 0;
        __syncthreads(); s[t] += u; __syncthreads();
    }
    if (t < nb) bsum[t] = s[t] - v;   // exclusive
}

__global__ void scan3_kernel(const int* __restrict__ incl, const int* __restrict__ cnt,
                             const int* __restrict__ bsum, int* __restrict__ rowptr,
                             int* __restrict__ cursor, int n, int E) {
    int i = blockIdx.x * blockDim.x + threadIdx.x;
    if (i < n) {
        int v = incl[i] - cnt[i] + bsum[i >> 8];
        rowptr[i] = v; cursor[i] = v;
    } else if (i == n) {
        rowptr[n] = E;
    }
}

__global__ void scatter_kernel(const int* __restrict__ dst, int* __restrict__ cursor,
                               int* __restrict__ perm, int E) {
    int e = blockIdx.x * blockDim.x + threadIdx.x;
    if (e < E) { int pos = atomicAdd(&cursor[dst[e]], 1); perm[pos] = e; }
}

// packed[i] = (rel<<24)|src  (CSR order) -- single 4B metadata word per edge
__global__ void pack_kernel(const int* __restrict__ perm, const int* __restrict__ rel,
                            const int* __restrict__ src, unsigned* __restrict__ packed, int E) {
    int i = blockIdx.x * blockDim.x + threadIdx.x;
    if (i < E) {
        int e = perm[i];
        packed[i] = ((unsigned)rel[e] << 24) | (unsigned)src[e];
    }
}

// ================= per-layer prep =================
__global__ void conv64_kernel(const float* __restrict__ in, unsigned short* __restrict__ out,
                              size_t n) {
    size_t i = (size_t)blockIdx.x * blockDim.x + threadIdx.x;
    if (i < n) out[i] = f2bf(in[i]);
}

// WbfT[r][e][k] = bf16(W[r][k][e])  (B-operand layout for MFMA)
__global__ void wconv_kernel(const float* __restrict__ W, unsigned short* __restrict__ WbfT,
                             int R) {
    int i = blockIdx.x * blockDim.x + threadIdx.x;
    if (i >= R * 4096) return;
    int r = i >> 12, rem = i & 4095, k = rem >> 6, e = rem & 63;
    WbfT[((size_t)(r * 64 + e)) * 64 + k] = f2bf(W[i]);
}

// Vb[r][0][d] = bf16(sum_e W[r,d,e] a_src[r,e]); row1 = a_dst
__global__ void compute_v_kernel(const float* __restrict__ W,
                                 const float* __restrict__ a_src,
                                 const float* __restrict__ a_dst,
                                 unsigned short* __restrict__ Vb, int R) {
    int idx = blockIdx.x * blockDim.x + threadIdx.x;   // r*64+d
    if (idx >= R * 64) return;
    int r = idx >> 6, d = idx & 63;
    const float* Wr = W + idx * 64;
    const float* as = a_src + r * 64;
    const float* ad = a_dst + r * 64;
    float s = 0.f, t = 0.f;
    for (int e = 0; e < 64; e++) { float w = Wr[e]; s = fmaf(w, as[e], s); t = fmaf(w, ad[e], t); }
    Vb[((size_t)r * 2 + 0) * 64 + d] = f2bf(s);
    Vb[((size_t)r * 2 + 1) * 64 + d] = f2bf(t);
}

// attS[n*R+r] = h[n,:].Vsrc[r,:] -- 64-node LDS tile, bf16 input
#define HPAD 68
__global__ __launch_bounds__(256) void att_gemm_b_kernel(
        const unsigned short* __restrict__ hb, const unsigned short* __restrict__ Vb,
        float* __restrict__ attS, float* __restrict__ attD, int N, int R) {
    __shared__ float hl[64 * HPAD];
    __shared__ float vl[16 * 64];   // [r*2+row][d], R<=8
    int t = threadIdx.x, n0 = blockIdx.x * 64;
    for (int i = t; i < 4096; i += 256) {
        int row = i >> 6, d = i & 63;
        int node = n0 + row;
        hl[row * HPAD + d] = (node < N) ? bf2f(hb[(size_t)node * 64 + d]) : 0.f;
    }
    for (int i = t; i < R * 128; i += 256) vl[i] = bf2f(Vb[i]);
    __syncthreads();
    for (int p = t; p < 64 * R; p += 256) {
        int node = p / R, r = p - node * R;
        int gn = n0 + node;
        if (gn >= N) continue;
        const float* hp = &hl[node * HPAD];
        const float* sp = &vl[(r * 2 + 0) * 64];
        const float* dp = &vl[(r * 2 + 1) * 64];
        float s = 0.f, dd = 0.f;
#pragma unroll 16
        for (int d = 0; d < 64; d++) {
            float hv = hp[d];
            s = fmaf(hv, sp[d], s);
            dd = fmaf(hv, dp[d], dd);
        }
        attS[(size_t)gn * R + r] = s;
        attD[(size_t)gn * R + r] = dd;
    }
}

// ====== pass 1: softmax + per-rel weighted h aggregation -> t[dst][r][64] bf16 ======
__global__ __launch_bounds__(256) void tbuild_kernel(
        const int* __restrict__ rowptr, const unsigned* __restrict__ packed,
        const float* __restrict__ attS, const float* __restrict__ attD,
        const unsigned short* __restrict__ hb, unsigned short* __restrict__ tb,
        int d0, int d1, int R, int shR) {
    int g = blockIdx.x * blockDim.x + threadIdx.x;
    int wv = d0 + (g >> 6), lane = g & 63;
    if (wv >= d1) return;
    int start = rowptr[wv], end = rowptr[wv + 1];
    int deg = end - start;
    float acc[8] = {0.f, 0.f, 0.f, 0.f, 0.f, 0.f, 0.f, 0.f};

    if (deg > 0 && deg <= 64) {
        int i = start + lane;
        bool act = i < end;
        unsigned p = act ? packed[i] : 0u;
        int r = p >> 24, s = p & 0xFFFFFFu;
        float sc = -INFINITY;
        if (act) {
            sc = attS[(size_t)s * R + r] + attD[((unsigned)wv << shR) + r];
            sc = sc > 0.f ? sc : NEG_SLOPE * sc;
        }
        float m = sc;
        for (int o = 32; o; o >>= 1) m = fmaxf(m, __shfl_xor(m, o));
        float ex = act ? expf(sc - m) : 0.f;
        float sum = ex;
        for (int o = 32; o; o >>= 1) sum += __shfl_xor(sum, o);
        float a = ex / (sum + 1e-9f);
        for (int k = 0; k < deg; k++) {
            unsigned pp = (unsigned)__shfl((int)p, k);
            float aa = __shfl(a, k);
            int rr = pp >> 24;
            unsigned ss = pp & 0xFFFFFFu;
            float hv = bf2f(hb[((size_t)ss << 6) + lane]);
#pragma unroll
            for (int q = 0; q < 8; q++)
                if (q == rr) acc[q] = fmaf(aa, hv, acc[q]);   // rr wave-uniform
        }
    } else if (deg > 64) {
        float m = -INFINITY;
        for (int base = start; base < end; base += 64) {
            int i = base + lane;
            if (i < end) {
                unsigned p = packed[i];
                int r = p >> 24, s = p & 0xFFFFFFu;
                float sc = attS[(size_t)s * R + r] + attD[((unsigned)wv << shR) + r];
                sc = sc > 0.f ? sc : NEG_SLOPE * sc;
                m = fmaxf(m, sc);
            }
        }
        for (int o = 32; o; o >>= 1) m = fmaxf(m, __shfl_xor(m, o));
        float sum = 0.f;
        for (int base = start; base < end; base += 64) {
            int i = base + lane;
            if (i < end) {
                unsigned p = packed[i];
                int r = p >> 24, s = p & 0xFFFFFFu;
                float sc = attS[(size_t)s * R + r] + attD[((unsigned)wv << shR) + r];
                sc = sc > 0.f ? sc : NEG_SLOPE * sc;
                sum += expf(sc - m);
            }
        }
        for (int o = 32; o; o >>= 1) sum += __shfl_xor(sum, o);
        float inv = 1.f / (sum + 1e-9f);
        for (int i = start; i < end; i++) {
            unsigned p = packed[i];   // wave-uniform
            int rr = p >> 24; unsigned ss = p & 0xFFFFFFu;
            float sc = attS[(size_t)ss * R + rr] + attD[((unsigned)wv << shR) + rr];
            sc = sc > 0.f ? sc : NEG_SLOPE * sc;
            float aa = expf(sc - m) * inv;
            float hv = bf2f(hb[((size_t)ss << 6) + lane]);
#pragma unroll
            for (int q = 0; q < 8; q++)
                if (q == rr) acc[q] = fmaf(aa, hv, acc[q]);
        }
    }

    size_t base = (size_t)(wv - d0) * R * 64;
    for (int r = 0; r < R; r++)
        tb[base + (size_t)r * 64 + lane] = f2bf(acc[r]);
}

// ====== pass 2: agg[dst] = ELU(sum_r t[dst,r] @ W[r]) via bf16 MFMA ======
// A[m=lane&15][k=8*quad+j] (m = node-in-tile), B[n][k] = WbfT, D[row=4*quad+reg][col=lane&15]
__global__ __launch_bounds__(256) void tgemm_kernel(
        const unsigned short* __restrict__ tb, const unsigned short* __restrict__ WbfT,
        unsigned short* __restrict__ hbOut, float* __restrict__ poolOut,
        const int* __restrict__ poolSeg, int poolStride,
        int d0, int d1, int R) {
    int t = threadIdx.x;
    int w = t >> 6, lane = t & 63;
    int quad = lane >> 4, m = lane & 15;
    int base = d0 + blockIdx.x * 64 + w * 16;   // 16 nodes per wave
    float4v acc[4] = {{0.f,0.f,0.f,0.f},{0.f,0.f,0.f,0.f},{0.f,0.f,0.f,0.f},{0.f,0.f,0.f,0.f}};

    for (int r = 0; r < R; r++) {
        int nodeA = base + m;
        short8 a0 = {}, a1 = {};
        if (nodeA < d1) {
            const unsigned short* ap = tb + ((size_t)(nodeA - d0) * R + r) * 64;
            a0 = *(const short8*)&ap[quad * 8];
            a1 = *(const short8*)&ap[32 + quad * 8];
        }
        const unsigned short* Bp = WbfT + (size_t)r * 4096;
#pragma unroll
        for (int c = 0; c < 4; c++) {
            short8 b0 = *(const short8*)&Bp[(c * 16 + m) * 64 + quad * 8];
            short8 b1 = *(const short8*)&Bp[(c * 16 + m) * 64 + 32 + quad * 8];
            acc[c] = __builtin_amdgcn_mfma_f32_16x16x32_bf16(a0, b0, acc[c], 0, 0, 0);
            acc[c] = __builtin_amdgcn_mfma_f32_16x16x32_bf16(a1, b1, acc[c], 0, 0, 0);
        }
    }

#pragma unroll
    for (int reg = 0; reg < 4; reg++) {
        int node = base + quad * 4 + reg;
        if (node >= d1) continue;
#pragma unroll
        for (int c = 0; c < 4; c++) {
            float v = acc[c][reg];
            v = v > 0.f ? v : expm1f(v);
            if (hbOut) hbOut[(size_t)node * 64 + c * 16 + m] = f2bf(v);
            if (poolOut) atomAddF(&poolOut[(size_t)poolSeg[node] * poolStride + c * 16 + m], v);
        }
    }
}

// feat[mol2rxn[m], 64:128] += mol[m]
__global__ void readout_mol_kernel(const float* __restrict__ mol,
                                   const int* __restrict__ mol2rxn,
                                   float* __restrict__ feat, int M) {
    int i = blockIdx.x * blockDim.x + threadIdx.x;
    if (i >= M * 64) return;
    int m = i >> 6, d = i & 63;
    atomAddF(&feat[(size_t)mol2rxn[m] * 128 + 64 + d], mol[i]);
}

// ================= MLP head: LDS-tiled GEMM =================
#define APAD 36
__global__ __launch_bounds__(256) void fc_gemm_kernel(
        const float* __restrict__ A, const float* __restrict__ B,
        const float* __restrict__ bias, const float* __restrict__ prelu,
        float* __restrict__ C, int M, int N, int K, int mode) {
    __shared__ float Al[64 * APAD];
    __shared__ float Bl[32 * 64];
    int t = threadIdx.x;
    int n0 = blockIdx.x * 64, m0 = blockIdx.y * 64;
    int e4 = (t & 15) * 4;
    int n4 = (t >> 4) * 4;
    float acc[4][4] = {};

    for (int k0 = 0; k0 < K; k0 += 32) {
        {
            const float4* Ag = (const float4*)A;
#pragma unroll
            for (int i = 0; i < 2; i++) {
                int idx = t + i * 256;
                int row = idx >> 3, c4 = idx & 7;
                float4 v = Ag[(size_t)(m0 + row) * (K >> 2) + (k0 >> 2) + c4];
                float* p = &Al[row * APAD + c4 * 4];
                p[0] = v.x; p[1] = v.y; p[2] = v.z; p[3] = v.w;
            }
        }
        {
#pragma unroll
            for (int i = 0; i < 2; i++) {
                int idx = t + i * 256;
                int kk = idx >> 4, c4 = (idx & 15) * 4;
                int col = n0 + c4;
                float4 v;
                const float* Brow = B + (size_t)(k0 + kk) * N;
                if (col + 3 < N) v = *(const float4*)&Brow[col];
                else {
                    v.x = (col + 0 < N) ? Brow[col + 0] : 0.f;
                    v.y = (col + 1 < N) ? Brow[col + 1] : 0.f;
                    v.z = (col + 2 < N) ? Brow[col + 2] : 0.f;
                    v.w = 0.f;
                }
                *(float4*)&Bl[kk * 64 + c4] = v;
            }
        }
        __syncthreads();
        for (int d = 0; d < 32; d += 4) {
            float4 wv[4], hv[4];
#pragma unroll
            for (int dd = 0; dd < 4; dd++) wv[dd] = *(const float4*)&Bl[(d + dd) * 64 + e4];
#pragma unroll
            for (int i = 0; i < 4; i++) hv[i] = *(const float4*)&Al[(n4 + i) * APAD + d];
#pragma unroll
            for (int i = 0; i < 4; i++) {
                const float hvv[4] = {hv[i].x, hv[i].y, hv[i].z, hv[i].w};
#pragma unroll
                for (int dd = 0; dd < 4; dd++) {
                    const float* wp = (const float*)&wv[dd];
#pragma unroll
                    for (int j = 0; j < 4; j++) acc[i][j] = fmaf(hvv[dd], wp[j], acc[i][j]);
                }
            }
        }
        __syncthreads();
    }

    float p = mode ? *prelu : 0.f;
#pragma unroll
    for (int i = 0; i < 4; i++) {
        int row = m0 + n4 + i;
#pragma unroll
        for (int j = 0; j < 4; j++) {
            int col = n0 + e4 + j;
            if (col < N) {
                float v = acc[i][j] + bias[col];
                if (mode) v = v > 0.f ? v : p * v;
                C[(size_t)row * N + col] = v;
            }
        }
    }
}

// ================= launch =================
extern "C" void kernel_launch(void* const* d_in, const int* in_sizes, int n_in,
                              void* d_out, int out_size, void* d_ws, size_t ws_size,
                              hipStream_t stream) {
    const float* node_feats = (const float*)d_in[0];
    const int*   edge_src   = (const int*)d_in[1];
    const int*   edge_dst   = (const int*)d_in[2];
    const int*   edge_rel   = (const int*)d_in[3];
    const int*   node2mol   = (const int*)d_in[4];
    const int*   rxn_src    = (const int*)d_in[5];
    const int*   rxn_dst    = (const int*)d_in[6];
    const int*   rxn_rel    = (const int*)d_in[7];
    const int*   mol2rxn    = (const int*)d_in[8];
    const float* W1     = (const float*)d_in[9];
    const float* a_src1 = (const float*)d_in[10];
    const float* a_dst1 = (const float*)d_in[11];
    const float* W2     = (const float*)d_in[12];
    const float* a_src2 = (const float*)d_in[13];
    const float* a_dst2 = (const float*)d_in[14];
    const float* Wr     = (const float*)d_in[15];
    const float* a_srcr = (const float*)d_in[16];
    const float* a_dstr = (const float*)d_in[17];
    const float* w_fc1  = (const float*)d_in[18];
    const float* b_fc1  = (const float*)d_in[19];
    const float* prelu1 = (const float*)d_in[20];
    const float* w_fc2  = (const float*)d_in[21];
    const float* b_fc2  = (const float*)d_in[22];

    const int N = 100000, E = 800000, M = 5000, ER = 40000;

    // ---- workspace layout ----
    unsigned short* hb0 = (unsigned short*)d_ws;        // 6.4M ush
    unsigned short* hb1 = hb0 + 6400000;                // 6.4M ush
    float* attS = (float*)(hb1 + 6400000);              // 800K f
    float* attD = attS + 800000;                        // 800K f
    unsigned* packed = (unsigned*)(attD + 800000);      // 800K
    float* mol  = (float*)(packed + 800000);            // 320K f
    unsigned short* molb = (unsigned short*)(mol + 320000);  // 320K ush
    float* feat = (float*)(molb + 320000);              // 131072 f
    float* hm   = feat + 131072;                        // 524288 f
    unsigned short* WbfT = (unsigned short*)(hm + 524288);   // 32768 ush
    unsigned short* Vb   = WbfT + 32768;                // 1024 ush
    int* rowptr = (int*)(Vb + 1024);                    // 100008
    // CSR scratch aliases head of tb region (disjoint in time):
    char* tail = (char*)(rowptr + 100008);
    int* cnt    = (int*)tail;                           // 100000
    int* incl   = cnt + 100000;
    int* bsum   = incl + 100000;                        // 512
    int* cursor = bsum + 512;
    int* perm   = cursor + 100000;                      // 800000
    unsigned short* tb = (unsigned short*)tail;         // t buffer, up to N*8*64 ush

    size_t tailBytes = (ws_size > (size_t)(tail - (char*)d_ws)) ? ws_size - (size_t)(tail - (char*)d_ws) : 0;
    size_t availUsh = tailBytes / 2;

    auto buildCSR = [&](const int* dstArr, const int* srcArr, const int* relArr, int n, int e) {
        hipMemsetAsync(cnt, 0, (size_t)n * sizeof(int), stream);
        hist_kernel<<<dim3((e + 255) / 256), 256, 0, stream>>>(dstArr, cnt, e);
        int nb = (n + 255) / 256;
        scan1_kernel<<<dim3(nb), 256, 0, stream>>>(cnt, incl, bsum, n);
        scan2_kernel<<<dim3(1), 512, 0, stream>>>(bsum, nb);
        scan3_kernel<<<dim3((n + 256) / 256), 256, 0, stream>>>(incl, cnt, bsum, rowptr, cursor, n, e);
        scatter_kernel<<<dim3((e + 255) / 256), 256, 0, stream>>>(dstArr, cursor, perm, e);
        pack_kernel<<<dim3((e + 255) / 256), 256, 0, stream>>>(perm, relArr, srcArr, packed, e);
    };

    auto rgat = [&](const unsigned short* hin, int n, const float* W,
                    const float* as, const float* ad, int R, int shR,
                    unsigned short* hbOut, float* poolOut, const int* poolSeg, int poolStride) {
        compute_v_kernel<<<dim3((R * 64 + 63) / 64), 64, 0, stream>>>(W, as, ad, Vb, R);
        wconv_kernel<<<dim3((R * 4096 + 255) / 256), 256, 0, stream>>>(W, WbfT, R);
        att_gemm_b_kernel<<<dim3((n + 63) / 64), 256, 0, stream>>>(hin, Vb, attS, attD, n, R);

        size_t perDst = (size_t)R * 64;
        int chunkN = (int)(availUsh / perDst);
        if (chunkN < 64) chunkN = 64;
        if (chunkN > n) chunkN = n;
        for (int d0 = 0; d0 < n; d0 += chunkN) {
            int d1 = d0 + chunkN; if (d1 > n) d1 = n;
            int cn = d1 - d0;
            tbuild_kernel<<<dim3(((size_t)cn * 64 + 255) / 256), 256, 0, stream>>>(
                rowptr, packed, attS, attD, hin, tb, d0, d1, R, shR);
            tgemm_kernel<<<dim3((cn + 63) / 64), 256, 0, stream>>>(
                tb, WbfT, hbOut, poolOut, poolSeg, poolStride, d0, d1, R);
        }
    };

    // ---- atom graph ----
    buildCSR(edge_dst, edge_src, edge_rel, N, E);
    conv64_kernel<<<dim3(((size_t)N * 64 + 255) / 256), 256, 0, stream>>>(node_feats, hb0, (size_t)N * 64);
    // layer 1 -> hb1 (bf16)
    rgat(hb0, N, W1, a_src1, a_dst1, 8, 3, hb1, nullptr, nullptr, 0);
    // layer 2 -> pooled directly into mol (fp32 atomics)
    hipMemsetAsync(mol, 0, (size_t)M * 64 * sizeof(float), stream);
    rgat(hb1, N, W2, a_src2, a_dst2, 8, 3, nullptr, mol, node2mol, 64);

    // ---- reaction graph ----
    conv64_kernel<<<dim3(((size_t)M * 64 + 255) / 256), 256, 0, stream>>>(mol, molb, (size_t)M * 64);
    buildCSR(rxn_dst, rxn_src, rxn_rel, M, ER);
    hipMemsetAsync(feat, 0, (size_t)1024 * 128 * sizeof(float), stream);
    rgat(molb, M, Wr, a_srcr, a_dstr, 4, 2, nullptr, feat, mol2rxn, 128);
    readout_mol_kernel<<<dim3(((size_t)M * 64 + 255) / 256), 256, 0, stream>>>(mol, mol2rxn, feat, M);

    // ---- MLP head ----
    fc_gemm_kernel<<<dim3(8, 16), 256, 0, stream>>>(feat, w_fc1, b_fc1, prelu1, hm, 1024, 512, 128, 1);
    fc_gemm_kernel<<<dim3(11, 16), 256, 0, stream>>>(hm, w_fc2, b_fc2, nullptr, (float*)d_out, 1024, 703, 512, 0);
}

// Round 11
// 578.289 us; speedup vs baseline: 1.3378x; 1.3378x over previous
//
#include <hip/hip_runtime.h>
#include <math.h>

#define NEG_SLOPE 0.2f

typedef __attribute__((ext_vector_type(8))) short short8;
typedef __attribute__((ext_vector_type(8))) unsigned short ushort8v;
typedef __attribute__((ext_vector_type(4))) float float4v;

__device__ __forceinline__ void atomAddF(float* p, float v) {
    unsafeAtomicAdd(p, v);   // HW global_atomic_add_f32 on gfx950
}
__device__ __forceinline__ unsigned short f2bf(float f) {
    unsigned u = __float_as_uint(f);
    unsigned r = (u + 0x7FFFu + ((u >> 16) & 1u)) >> 16;   // RNE
    return (unsigned short)r;
}
__device__ __forceinline__ float bf2f(unsigned short b) {
    return __uint_as_float((unsigned)b << 16);
}

// ================= CSR build (counting sort by dst) =================
__global__ void hist_kernel(const int* __restrict__ dst, int* __restrict__ cnt, int E) {
    int e = blockIdx.x * blockDim.x + threadIdx.x;
    if (e < E) atomicAdd(&cnt[dst[e]], 1);
}

__global__ void scan1_kernel(const int* __restrict__ cnt, int* __restrict__ incl,
                             int* __restrict__ bsum, int n) {
    __shared__ int s[256];
    int t = threadIdx.x, i = blockIdx.x * 256 + t;
    int v = (i < n) ? cnt[i] : 0;
    s[t] = v; __syncthreads();
    for (int o = 1; o < 256; o <<= 1) {
        int u = (t >= o) ? s[t - o] : 0;
        __syncthreads(); s[t] += u; __syncthreads();
    }
    if (i < n) incl[i] = s[t];
    if (t == 255) bsum[blockIdx.x] = s[255];
}

__global__ void scan2_kernel(int* __restrict__ bsum, int nb) {
    __shared__ int s[512];
    int t = threadIdx.x;
    int v = (t < nb) ? bsum[t] : 0;
    s[t] = v; __syncthreads();
    for (int o = 1; o < 512; o <<= 1) {
        int u = (t >= o) ? s[t - o] : 0;
        __syncthreads(); s[t] += u; __syncthreads();
    }
    if (t < nb) bsum[t] = s[t] - v;   // exclusive
}

__global__ void scan3_kernel(const int* __restrict__ incl, const int* __restrict__ cnt,
                             const int* __restrict__ bsum, int* __restrict__ rowptr,
                             int* __restrict__ cursor, int n, int E) {
    int i = blockIdx.x * blockDim.x + threadIdx.x;
    if (i < n) {
        int v = incl[i] - cnt[i] + bsum[i >> 8];
        rowptr[i] = v; cursor[i] = v;
    } else if (i == n) {
        rowptr[n] = E;
    }
}

__global__ void scatter_kernel(const int* __restrict__ dst, int* __restrict__ cursor,
                               int* __restrict__ perm, int E) {
    int e = blockIdx.x * blockDim.x + threadIdx.x;
    if (e < E) { int pos = atomicAdd(&cursor[dst[e]], 1); perm[pos] = e; }
}

// packed[i] = (rel[perm[i]]<<24) | src[perm[i]]  (src < 2^24)
__global__ void pack_kernel(const int* __restrict__ perm, const int* __restrict__ rel,
                            const int* __restrict__ src, unsigned* __restrict__ packed, int E) {
    int i = blockIdx.x * blockDim.x + threadIdx.x;
    if (i < E) {
        int e = perm[i];
        packed[i] = ((unsigned)rel[e] << 24) | (unsigned)src[e];
    }
}

// ================= RGAT =================
__global__ void compute_v_kernel(const float* __restrict__ W,
                                 const float* __restrict__ a_src,
                                 const float* __restrict__ a_dst,
                                 float* __restrict__ Vsrc, float* __restrict__ Vdst,
                                 int R) {
    int idx = blockIdx.x * blockDim.x + threadIdx.x;   // r*64+d
    if (idx >= R * 64) return;
    int r = idx >> 6;
    const float* Wr = W + idx * 64;
    const float* as = a_src + r * 64;
    const float* ad = a_dst + r * 64;
    float s = 0.f, t = 0.f;
    for (int e = 0; e < 64; e++) { float w = Wr[e]; s = fmaf(w, as[e], s); t = fmaf(w, ad[e], t); }
    Vsrc[idx] = s; Vdst[idx] = t;
}

// attS[n*R+r] = h[n,:] . Vsrc[r,:]  -- skinny GEMM, 64-node LDS tile (fp32)
#define HPAD 68
__global__ __launch_bounds__(256) void att_gemm_kernel(
        const float* __restrict__ h,
        const float* __restrict__ Vsrc, const float* __restrict__ Vdst,
        float* __restrict__ attS, float* __restrict__ attD,
        int N, int R) {
    __shared__ float hl[64 * HPAD];
    __shared__ float Vs[8 * HPAD];
    __shared__ float Vd[8 * HPAD];
    int t = threadIdx.x;
    int n0 = blockIdx.x * 64;

    {
        const float4* hg = (const float4*)h;
#pragma unroll
        for (int i = 0; i < 4; i++) {
            int idx = t + i * 256;
            int row = idx >> 4, col4 = idx & 15;
            int node = n0 + row;
            float4 v = (node < N) ? hg[(size_t)node * 16 + col4] : float4{0.f, 0.f, 0.f, 0.f};
            *(float4*)&hl[row * HPAD + col4 * 4] = v;
        }
    }
    for (int i = t; i < R * 64; i += 256) {
        int r = i >> 6, d = i & 63;
        Vs[r * HPAD + d] = Vsrc[i];
        Vd[r * HPAD + d] = Vdst[i];
    }
    __syncthreads();

    for (int p = t; p < 64 * R; p += 256) {
        int node = p / R, r = p - node * R;
        const float4* hp = (const float4*)&hl[node * HPAD];
        const float4* sp = (const float4*)&Vs[r * HPAD];
        const float4* dp = (const float4*)&Vd[r * HPAD];
        float s = 0.f, dd = 0.f;
#pragma unroll
        for (int d4 = 0; d4 < 16; d4++) {
            float4 hv = hp[d4], sv = sp[d4], dv = dp[d4];
            s  = fmaf(hv.x, sv.x, s);  s  = fmaf(hv.y, sv.y, s);
            s  = fmaf(hv.z, sv.z, s);  s  = fmaf(hv.w, sv.w, s);
            dd = fmaf(hv.x, dv.x, dd); dd = fmaf(hv.y, dv.y, dd);
            dd = fmaf(hv.z, dv.z, dd); dd = fmaf(hv.w, dv.w, dd);
        }
        int gn = n0 + node;
        if (gn < N) { attS[(size_t)gn * R + r] = s; attD[(size_t)gn * R + r] = dd; }
    }
}

// hW[rl,n,e] via bf16 MFMA; h tile staged+converted ONCE, loop relations.
// A[m=lane&15][k=8*quad+j], B[n=lane&15][k=8*quad+j], D[row=4*quad+reg][col=lane&15]
#define BSTRIDE 72
__global__ __launch_bounds__(256) void hw_gemm_mfma_kernel(
        const float* __restrict__ h, const float* __restrict__ W,
        unsigned short* __restrict__ hWb, int N, int r0, int r1) {
    __shared__ unsigned short hb[64 * BSTRIDE];
    __shared__ unsigned short wt[64 * BSTRIDE];
    int t = threadIdx.x;
    int n0 = blockIdx.x * 64;

    {
        const float4* hg = (const float4*)h;
#pragma unroll
        for (int i = 0; i < 4; i++) {
            int idx = t + i * 256;
            int row = idx >> 4, c4 = idx & 15;
            int node = n0 + row;
            float4 v = (node < N) ? hg[(size_t)node * 16 + c4] : float4{0.f, 0.f, 0.f, 0.f};
            ushort4 b;
            b.x = f2bf(v.x); b.y = f2bf(v.y); b.z = f2bf(v.z); b.w = f2bf(v.w);
            *(ushort4*)&hb[row * BSTRIDE + c4 * 4] = b;
        }
    }
    __syncthreads();

    int w = t >> 6, lane = t & 63;
    int quad = lane >> 4, m = lane & 15;
    int arow = w * 16 + m;
    short8 a0 = *(const short8*)&hb[arow * BSTRIDE + quad * 8];
    short8 a1 = *(const short8*)&hb[arow * BSTRIDE + 32 + quad * 8];

    for (int r = r0; r < r1; r++) {
        __syncthreads();
        {
            const float4* Wg = (const float4*)(W + (size_t)r * 4096);
#pragma unroll
            for (int i = 0; i < 4; i++) {
                int idx = t + i * 256;
                int k = idx >> 4, e4 = (idx & 15) * 4;
                float4 v = Wg[idx];
                wt[(e4 + 0) * BSTRIDE + k] = f2bf(v.x);
                wt[(e4 + 1) * BSTRIDE + k] = f2bf(v.y);
                wt[(e4 + 2) * BSTRIDE + k] = f2bf(v.z);
                wt[(e4 + 3) * BSTRIDE + k] = f2bf(v.w);
            }
        }
        __syncthreads();

        size_t outBase = ((size_t)(r - r0) * N + n0 + w * 16) * 64;
#pragma unroll
        for (int c = 0; c < 4; c++) {
            short8 b0 = *(const short8*)&wt[(c * 16 + m) * BSTRIDE + quad * 8];
            short8 b1 = *(const short8*)&wt[(c * 16 + m) * BSTRIDE + 32 + quad * 8];
            float4v acc = {0.f, 0.f, 0.f, 0.f};
            acc = __builtin_amdgcn_mfma_f32_16x16x32_bf16(a0, b0, acc, 0, 0, 0);
            acc = __builtin_amdgcn_mfma_f32_16x16x32_bf16(a1, b1, acc, 0, 0, 0);
#pragma unroll
            for (int reg = 0; reg < 4; reg++) {
                int node = n0 + w * 16 + quad * 4 + reg;
                if (node < N)
                    hWb[outBase + (size_t)(quad * 4 + reg) * 64 + c * 16 + m] = f2bf(acc[reg]);
            }
        }
    }
}

// ====== fused softmax + aggregation, GROUPED GATHER ======
// Phase 1: lane=edge softmax (unchanged from R8). Phase 2: lane=(edge_slot*8+dim_group):
// one VMEM instruction gathers 8 edges' full 64-dim bf16 rows (64 lanes x 16 B);
// cross-edge reduce via 3 shfl_xor butterfly steps (masks 8/16/32).
__global__ __launch_bounds__(256) void aggsoft_kernel(
        const int* __restrict__ rowptr, const unsigned* __restrict__ packed,
        const float* __restrict__ attS, const float* __restrict__ attD,
        const unsigned short* __restrict__ hWb, float* __restrict__ agg,
        int n, int N, int R, int r0, int r1, int last) {
    int g = blockIdx.x * blockDim.x + threadIdx.x;
    int wv = g >> 6, lane = g & 63;
    if (wv >= n) return;
    int start = rowptr[wv], end = rowptr[wv + 1];
    int deg = end - start;
    int egrp = lane >> 3, dgrp = lane & 7;

    float acc8[8] = {0.f, 0.f, 0.f, 0.f, 0.f, 0.f, 0.f, 0.f};
    if (r0 != 0) {
#pragma unroll
        for (int j = 0; j < 8; j += 4) {
            float4 v = *(const float4*)&agg[(size_t)wv * 64 + dgrp * 8 + j];
            acc8[j] = v.x; acc8[j + 1] = v.y; acc8[j + 2] = v.z; acc8[j + 3] = v.w;
        }
    }

    if (deg > 0 && deg <= 64) {
        // phase 1: softmax over edges (lane = edge)
        int i = start + lane;
        bool act = i < end;
        unsigned p = act ? packed[i] : 0u;
        int r = p >> 24; unsigned s = p & 0xFFFFFFu;
        float sc = -INFINITY;
        if (act) {
            sc = attS[(size_t)s * R + r] + attD[(size_t)wv * R + r];
            sc = sc > 0.f ? sc : NEG_SLOPE * sc;
        }
        float m = sc;
        for (int o = 32; o; o >>= 1) m = fmaxf(m, __shfl_xor(m, o));
        float ex = act ? expf(sc - m) : 0.f;
        float sum = ex;
        for (int o = 32; o; o >>= 1) sum += __shfl_xor(sum, o);
        float a = ex / (sum + 1e-9f);
        float ag = (act && r >= r0 && r < r1) ? a : 0.f;   // gate to this hW chunk

        // phase 2: grouped gather — 8 edges per chunk, full rows in parallel
        int nchunk = (deg + 7) >> 3;
        for (int c = 0; c < nchunk; c++) {
            int el = c * 8 + egrp;            // edge slot served by this lane group
            float aa = __shfl(ag, el);
            unsigned pp = (unsigned)__shfl((int)p, el);
            if (aa != 0.f) {
                unsigned row = (unsigned)(((pp >> 24) - r0) * (unsigned)N) + (pp & 0xFFFFFFu);
                ushort8v v = *(const ushort8v*)&hWb[((size_t)row << 6) + dgrp * 8];
#pragma unroll
                for (int j = 0; j < 8; j++) acc8[j] = fmaf(aa, bf2f(v[j]), acc8[j]);
            }
        }
        // butterfly reduce across edge groups (xor bits 3..5)
#pragma unroll
        for (int msk = 8; msk <= 32; msk <<= 1)
#pragma unroll
            for (int j = 0; j < 8; j++) acc8[j] += __shfl_xor(acc8[j], msk);
    } else if (deg > 64) {
        // rare fallback: two-pass softmax stats, then grouped gather w/ recompute
        float m = -INFINITY;
        for (int base = start; base < end; base += 64) {
            int i = base + lane;
            if (i < end) {
                unsigned p = packed[i];
                int r = p >> 24; unsigned s = p & 0xFFFFFFu;
                float sc = attS[(size_t)s * R + r] + attD[(size_t)wv * R + r];
                sc = sc > 0.f ? sc : NEG_SLOPE * sc;
                m = fmaxf(m, sc);
            }
        }
        for (int o = 32; o; o >>= 1) m = fmaxf(m, __shfl_xor(m, o));
        float sum = 0.f;
        for (int base = start; base < end; base += 64) {
            int i = base + lane;
            if (i < end) {
                unsigned p = packed[i];
                int r = p >> 24; unsigned s = p & 0xFFFFFFu;
                float sc = attS[(size_t)s * R + r] + attD[(size_t)wv * R + r];
                sc = sc > 0.f ? sc : NEG_SLOPE * sc;
                sum += expf(sc - m);
            }
        }
        for (int o = 32; o; o >>= 1) sum += __shfl_xor(sum, o);
        float inv = 1.f / (sum + 1e-9f);
        int nchunk = (deg + 7) >> 3;
        for (int c = 0; c < nchunk; c++) {
            int el = c * 8 + egrp;
            if (el < deg) {
                unsigned p = packed[start + el];   // uniform within e-group
                int r = p >> 24; unsigned s = p & 0xFFFFFFu;
                if (r >= r0 && r < r1) {
                    float sc = attS[(size_t)s * R + r] + attD[(size_t)wv * R + r];
                    sc = sc > 0.f ? sc : NEG_SLOPE * sc;
                    float aa = expf(sc - m) * inv;
                    unsigned row = (unsigned)((r - r0) * N) + s;
                    ushort8v v = *(const ushort8v*)&hWb[((size_t)row << 6) + dgrp * 8];
#pragma unroll
                    for (int j = 0; j < 8; j++) acc8[j] = fmaf(aa, bf2f(v[j]), acc8[j]);
                }
            }
        }
#pragma unroll
        for (int msk = 8; msk <= 32; msk <<= 1)
#pragma unroll
            for (int j = 0; j < 8; j++) acc8[j] += __shfl_xor(acc8[j], msk);
    }

    if (last) {
#pragma unroll
        for (int j = 0; j < 8; j++) acc8[j] = acc8[j] > 0.f ? acc8[j] : expm1f(acc8[j]);
    }
    if (egrp == 0) {   // lanes 0..7 write the 64-dim row (dims dgrp*8..+7)
        float4 v0 = {acc8[0], acc8[1], acc8[2], acc8[3]};
        float4 v1 = {acc8[4], acc8[5], acc8[6], acc8[7]};
        *(float4*)&agg[(size_t)wv * 64 + dgrp * 8] = v0;
        *(float4*)&agg[(size_t)wv * 64 + dgrp * 8 + 4] = v1;
    }
}

// ================= pooling / readout =================
__global__ void seg_sum64_kernel(const float* __restrict__ h, const int* __restrict__ seg,
                                 float* __restrict__ out, int N) {
    int i = blockIdx.x * blockDim.x + threadIdx.x;
    if (i >= N * 64) return;
    int n = i >> 6, d = i & 63;
    atomAddF(&out[seg[n] * 64 + d], h[i]);
}

__global__ void readout_kernel(const float* __restrict__ molr, const float* __restrict__ mol,
                               const int* __restrict__ mol2rxn, float* __restrict__ feat, int M) {
    int i = blockIdx.x * blockDim.x + threadIdx.x;
    if (i >= M * 64) return;
    int m = i >> 6, d = i & 63;
    int b = mol2rxn[m];
    atomAddF(&feat[b * 128 + d], molr[i]);
    atomAddF(&feat[b * 128 + 64 + d], mol[i]);
}

// ================= MLP head: LDS-tiled GEMM =================
#define APAD 36
__global__ __launch_bounds__(256) void fc_gemm_kernel(
        const float* __restrict__ A, const float* __restrict__ B,
        const float* __restrict__ bias, const float* __restrict__ prelu,
        float* __restrict__ C, int M, int N, int K, int mode) {
    __shared__ float Al[64 * APAD];
    __shared__ float Bl[32 * 64];
    int t = threadIdx.x;
    int n0 = blockIdx.x * 64, m0 = blockIdx.y * 64;
    int e4 = (t & 15) * 4;
    int n4 = (t >> 4) * 4;
    float acc[4][4] = {};

    for (int k0 = 0; k0 < K; k0 += 32) {
        {
            const float4* Ag = (const float4*)A;
#pragma unroll
            for (int i = 0; i < 2; i++) {
                int idx = t + i * 256;
                int row = idx >> 3, c4 = idx & 7;
                float4 v = Ag[(size_t)(m0 + row) * (K >> 2) + (k0 >> 2) + c4];
                float* p = &Al[row * APAD + c4 * 4];
                p[0] = v.x; p[1] = v.y; p[2] = v.z; p[3] = v.w;
            }
        }
        {
#pragma unroll
            for (int i = 0; i < 2; i++) {
                int idx = t + i * 256;
                int kk = idx >> 4, c4 = (idx & 15) * 4;
                int col = n0 + c4;
                float4 v;
                const float* Brow = B + (size_t)(k0 + kk) * N;
                if (col + 3 < N) v = *(const float4*)&Brow[col];
                else {
                    v.x = (col + 0 < N) ? Brow[col + 0] : 0.f;
                    v.y = (col + 1 < N) ? Brow[col + 1] : 0.f;
                    v.z = (col + 2 < N) ? Brow[col + 2] : 0.f;
                    v.w = 0.f;
                }
                *(float4*)&Bl[kk * 64 + c4] = v;
            }
        }
        __syncthreads();
        for (int d = 0; d < 32; d += 4) {
            float4 wv[4], hv[4];
#pragma unroll
            for (int dd = 0; dd < 4; dd++) wv[dd] = *(const float4*)&Bl[(d + dd) * 64 + e4];
#pragma unroll
            for (int i = 0; i < 4; i++) hv[i] = *(const float4*)&Al[(n4 + i) * APAD + d];
#pragma unroll
            for (int i = 0; i < 4; i++) {
                const float hvv[4] = {hv[i].x, hv[i].y, hv[i].z, hv[i].w};
#pragma unroll
                for (int dd = 0; dd < 4; dd++) {
                    const float* wp = (const float*)&wv[dd];
#pragma unroll
                    for (int j = 0; j < 4; j++) acc[i][j] = fmaf(hvv[dd], wp[j], acc[i][j]);
                }
            }
        }
        __syncthreads();
    }

    float p = mode ? *prelu : 0.f;
#pragma unroll
    for (int i = 0; i < 4; i++) {
        int row = m0 + n4 + i;
#pragma unroll
        for (int j = 0; j < 4; j++) {
            int col = n0 + e4 + j;
            if (col < N) {
                float v = acc[i][j] + bias[col];
                if (mode) v = v > 0.f ? v : p * v;
                C[(size_t)row * N + col] = v;
            }
        }
    }
}

// ================= launch =================
extern "C" void kernel_launch(void* const* d_in, const int* in_sizes, int n_in,
                              void* d_out, int out_size, void* d_ws, size_t ws_size,
                              hipStream_t stream) {
    const float* node_feats = (const float*)d_in[0];
    const int*   edge_src   = (const int*)d_in[1];
    const int*   edge_dst   = (const int*)d_in[2];
    const int*   edge_rel   = (const int*)d_in[3];
    const int*   node2mol   = (const int*)d_in[4];
    const int*   rxn_src    = (const int*)d_in[5];
    const int*   rxn_dst    = (const int*)d_in[6];
    const int*   rxn_rel    = (const int*)d_in[7];
    const int*   mol2rxn    = (const int*)d_in[8];
    const float* W1     = (const float*)d_in[9];
    const float* a_src1 = (const float*)d_in[10];
    const float* a_dst1 = (const float*)d_in[11];
    const float* W2     = (const float*)d_in[12];
    const float* a_src2 = (const float*)d_in[13];
    const float* a_dst2 = (const float*)d_in[14];
    const float* Wr     = (const float*)d_in[15];
    const float* a_srcr = (const float*)d_in[16];
    const float* a_dstr = (const float*)d_in[17];
    const float* w_fc1  = (const float*)d_in[18];
    const float* b_fc1  = (const float*)d_in[19];
    const float* prelu1 = (const float*)d_in[20];
    const float* w_fc2  = (const float*)d_in[21];
    const float* b_fc2  = (const float*)d_in[22];

    const int N = 100000, E = 800000, M = 5000, ER = 40000;

    float* ws = (float*)d_ws;
    float* h1     = ws;                       // 6,400,000
    float* h2     = h1 + 6400000;             // 6,400,000
    float* attS   = h2 + 6400000;             // 800,000
    float* attD   = attS + 800000;            // 800,000
    float* mol    = attD + 800000;            // 320,000
    float* molr   = mol + 320000;             // 320,000
    float* feat   = molr + 320000;            // 131,072
    float* hm     = feat + 131072;            // 524,288
    float* Vsrc   = hm + 524288;              // 512
    float* Vdst   = Vsrc + 512;               // 512
    int* rowptr   = (int*)(Vdst + 512);       // 100,008
    int* cnt      = rowptr + 100008;          // 100,000
    int* incl     = cnt + 100000;             // 100,000
    int* bsum     = incl + 100000;            // 512
    int* cursor   = bsum + 512;               // 100,000
    int* perm     = cursor + 100000;          // 800,000
    unsigned* packed = (unsigned*)(perm + 800000);           // 800,000
    unsigned short* hWb = (unsigned short*)(packed + 800000); // bf16 hW (chunked)

    size_t usedBytes = (size_t)((char*)hWb - (char*)d_ws);
    size_t availUshorts = (ws_size > usedBytes) ? (ws_size - usedBytes) / 2 : 0;

    auto buildCSR = [&](const int* dstArr, const int* srcArr, const int* relArr, int n, int e) {
        hipMemsetAsync(cnt, 0, (size_t)n * sizeof(int), stream);
        hist_kernel<<<dim3((e + 255) / 256), 256, 0, stream>>>(dstArr, cnt, e);
        int nb = (n + 255) / 256;
        scan1_kernel<<<dim3(nb), 256, 0, stream>>>(cnt, incl, bsum, n);
        scan2_kernel<<<dim3(1), 512, 0, stream>>>(bsum, nb);
        scan3_kernel<<<dim3((n + 256) / 256), 256, 0, stream>>>(incl, cnt, bsum, rowptr, cursor, n, e);
        scatter_kernel<<<dim3((e + 255) / 256), 256, 0, stream>>>(dstArr, cursor, perm, e);
        pack_kernel<<<dim3((e + 255) / 256), 256, 0, stream>>>(perm, relArr, srcArr, packed, e);
    };

    auto rgat = [&](const float* hin, int n,
                    const float* W, const float* as, const float* ad,
                    float* agg, int R) {
        compute_v_kernel<<<dim3((R * 64 + 63) / 64), 64, 0, stream>>>(W, as, ad, Vsrc, Vdst, R);
        att_gemm_kernel<<<dim3((n + 63) / 64), 256, 0, stream>>>(hin, Vsrc, Vdst, attS, attD, n, R);

        size_t perRel = (size_t)n * 64;   // ushorts per relation
        int chunk = (int)(availUshorts / perRel);
        if (chunk < 1) chunk = 1;
        if (chunk > R) chunk = R;
        for (int r0 = 0; r0 < R; r0 += chunk) {
            int r1 = r0 + chunk; if (r1 > R) r1 = R;
            hw_gemm_mfma_kernel<<<dim3((n + 63) / 64), 256, 0, stream>>>(hin, W, hWb, n, r0, r1);
            aggsoft_kernel<<<dim3(((size_t)n * 64 + 255) / 256), 256, 0, stream>>>(
                rowptr, packed, attS, attD, hWb, agg, n, n, R, r0, r1, r1 == R ? 1 : 0);
        }
    };

    // ---- atom graph CSR (shared by both atom layers) ----
    buildCSR(edge_dst, edge_src, edge_rel, N, E);
    rgat(node_feats, N, W1, a_src1, a_dst1, h1, 8);
    rgat(h1,         N, W2, a_src2, a_dst2, h2, 8);

    // ---- molecule pooling ----
    hipMemsetAsync(mol, 0, (size_t)M * 64 * sizeof(float), stream);
    seg_sum64_kernel<<<dim3(((size_t)N * 64 + 255) / 256), 256, 0, stream>>>(h2, node2mol, mol, N);

    // ---- reaction-graph RGAT ----
    buildCSR(rxn_dst, rxn_src, rxn_rel, M, ER);
    rgat(mol, M, Wr, a_srcr, a_dstr, molr, 4);

    // ---- reaction readout ----
    hipMemsetAsync(feat, 0, (size_t)1024 * 128 * sizeof(float), stream);
    readout_kernel<<<dim3(((size_t)M * 64 + 255) / 256), 256, 0, stream>>>(molr, mol, mol2rxn, feat, M);

    // ---- MLP head: tiled GEMMs ----
    fc_gemm_kernel<<<dim3(8, 16), 256, 0, stream>>>(feat, w_fc1, b_fc1, prelu1, hm, 1024, 512, 128, 1);
    fc_gemm_kernel<<<dim3(11, 16), 256, 0, stream>>>(hm, w_fc2, b_fc2, nullptr, (float*)d_out, 1024, 703, 512, 0);
}

// Round 12
// 564.797 us; speedup vs baseline: 1.3697x; 1.0239x over previous
//
#include <hip/hip_runtime.h>
#include <math.h>

#define NEG_SLOPE 0.2f

typedef __attribute__((ext_vector_type(8))) short short8;
typedef __attribute__((ext_vector_type(8))) unsigned short ushort8v;
typedef __attribute__((ext_vector_type(4))) float float4v;

__device__ __forceinline__ void atomAddF(float* p, float v) {
    unsafeAtomicAdd(p, v);   // HW global_atomic_add_f32 on gfx950
}
__device__ __forceinline__ unsigned short f2bf(float f) {
    unsigned u = __float_as_uint(f);
    unsigned r = (u + 0x7FFFu + ((u >> 16) & 1u)) >> 16;   // RNE
    return (unsigned short)r;
}
__device__ __forceinline__ float bf2f(unsigned short b) {
    return __uint_as_float((unsigned)b << 16);
}

// ================= CSR build (counting sort by dst) =================
__global__ void hist_kernel(const int* __restrict__ dst, int* __restrict__ cnt, int E) {
    int e = blockIdx.x * blockDim.x + threadIdx.x;
    if (e < E) atomicAdd(&cnt[dst[e]], 1);
}

__global__ void scan1_kernel(const int* __restrict__ cnt, int* __restrict__ incl,
                             int* __restrict__ bsum, int n) {
    __shared__ int s[256];
    int t = threadIdx.x, i = blockIdx.x * 256 + t;
    int v = (i < n) ? cnt[i] : 0;
    s[t] = v; __syncthreads();
    for (int o = 1; o < 256; o <<= 1) {
        int u = (t >= o) ? s[t - o] : 0;
        __syncthreads(); s[t] += u; __syncthreads();
    }
    if (i < n) incl[i] = s[t];
    if (t == 255) bsum[blockIdx.x] = s[255];
}

__global__ void scan2_kernel(int* __restrict__ bsum, int nb) {
    __shared__ int s[512];
    int t = threadIdx.x;
    int v = (t < nb) ? bsum[t] : 0;
    s[t] = v; __syncthreads();
    for (int o = 1; o < 512; o <<= 1) {
        int u = (t >= o) ? s[t - o] : 0;
        __syncthreads(); s[t] += u; __syncthreads();
    }
    if (t < nb) bsum[t] = s[t] - v;   // exclusive
}

__global__ void scan3_kernel(const int* __restrict__ incl, const int* __restrict__ cnt,
                             const int* __restrict__ bsum, int* __restrict__ rowptr,
                             int* __restrict__ cursor, int n, int E) {
    int i = blockIdx.x * blockDim.x + threadIdx.x;
    if (i < n) {
        int v = incl[i] - cnt[i] + bsum[i >> 8];
        rowptr[i] = v; cursor[i] = v;
    } else if (i == n) {
        rowptr[n] = E;
    }
}

__global__ void scatter_kernel(const int* __restrict__ dst, int* __restrict__ cursor,
                               int* __restrict__ perm, int E) {
    int e = blockIdx.x * blockDim.x + threadIdx.x;
    if (e < E) { int pos = atomicAdd(&cursor[dst[e]], 1); perm[pos] = e; }
}

// packed[i] = (rel[perm[i]]<<24) | src[perm[i]]  (src < 2^24)
__global__ void pack_kernel(const int* __restrict__ perm, const int* __restrict__ rel,
                            const int* __restrict__ src, unsigned* __restrict__ packed, int E) {
    int i = blockIdx.x * blockDim.x + threadIdx.x;
    if (i < E) {
        int e = perm[i];
        packed[i] = ((unsigned)rel[e] << 24) | (unsigned)src[e];
    }
}

// ================= RGAT =================
__global__ void compute_v_kernel(const float* __restrict__ W,
                                 const float* __restrict__ a_src,
                                 const float* __restrict__ a_dst,
                                 float* __restrict__ Vsrc, float* __restrict__ Vdst,
                                 int R) {
    int idx = blockIdx.x * blockDim.x + threadIdx.x;   // r*64+d
    if (idx >= R * 64) return;
    int r = idx >> 6;
    const float* Wr = W + idx * 64;
    const float* as = a_src + r * 64;
    const float* ad = a_dst + r * 64;
    float s = 0.f, t = 0.f;
    for (int e = 0; e < 64; e++) { float w = Wr[e]; s = fmaf(w, as[e], s); t = fmaf(w, ad[e], t); }
    Vsrc[idx] = s; Vdst[idx] = t;
}

// attS[n*R+r] = h[n,:] . Vsrc[r,:]  -- skinny GEMM, 64-node LDS tile (fp32)
#define HPAD 68
__global__ __launch_bounds__(256) void att_gemm_kernel(
        const float* __restrict__ h,
        const float* __restrict__ Vsrc, const float* __restrict__ Vdst,
        float* __restrict__ attS, float* __restrict__ attD,
        int N, int R) {
    __shared__ float hl[64 * HPAD];
    __shared__ float Vs[8 * HPAD];
    __shared__ float Vd[8 * HPAD];
    int t = threadIdx.x;
    int n0 = blockIdx.x * 64;

    {
        const float4* hg = (const float4*)h;
#pragma unroll
        for (int i = 0; i < 4; i++) {
            int idx = t + i * 256;
            int row = idx >> 4, col4 = idx & 15;
            int node = n0 + row;
            float4 v = (node < N) ? hg[(size_t)node * 16 + col4] : float4{0.f, 0.f, 0.f, 0.f};
            *(float4*)&hl[row * HPAD + col4 * 4] = v;
        }
    }
    for (int i = t; i < R * 64; i += 256) {
        int r = i >> 6, d = i & 63;
        Vs[r * HPAD + d] = Vsrc[i];
        Vd[r * HPAD + d] = Vdst[i];
    }
    __syncthreads();

    for (int p = t; p < 64 * R; p += 256) {
        int node = p / R, r = p - node * R;
        const float4* hp = (const float4*)&hl[node * HPAD];
        const float4* sp = (const float4*)&Vs[r * HPAD];
        const float4* dp = (const float4*)&Vd[r * HPAD];
        float s = 0.f, dd = 0.f;
#pragma unroll
        for (int d4 = 0; d4 < 16; d4++) {
            float4 hv = hp[d4], sv = sp[d4], dv = dp[d4];
            s  = fmaf(hv.x, sv.x, s);  s  = fmaf(hv.y, sv.y, s);
            s  = fmaf(hv.z, sv.z, s);  s  = fmaf(hv.w, sv.w, s);
            dd = fmaf(hv.x, dv.x, dd); dd = fmaf(hv.y, dv.y, dd);
            dd = fmaf(hv.z, dv.z, dd); dd = fmaf(hv.w, dv.w, dd);
        }
        int gn = n0 + node;
        if (gn < N) { attS[(size_t)gn * R + r] = s; attD[(size_t)gn * R + r] = dd; }
    }
}

// hW[rl,n,e] via bf16 MFMA; h tile staged+converted ONCE, loop relations.
#define BSTRIDE 72
__global__ __launch_bounds__(256) void hw_gemm_mfma_kernel(
        const float* __restrict__ h, const float* __restrict__ W,
        unsigned short* __restrict__ hWb, int N, int r0, int r1) {
    __shared__ unsigned short hb[64 * BSTRIDE];
    __shared__ unsigned short wt[64 * BSTRIDE];
    int t = threadIdx.x;
    int n0 = blockIdx.x * 64;

    {
        const float4* hg = (const float4*)h;
#pragma unroll
        for (int i = 0; i < 4; i++) {
            int idx = t + i * 256;
            int row = idx >> 4, c4 = idx & 15;
            int node = n0 + row;
            float4 v = (node < N) ? hg[(size_t)node * 16 + c4] : float4{0.f, 0.f, 0.f, 0.f};
            ushort4 b;
            b.x = f2bf(v.x); b.y = f2bf(v.y); b.z = f2bf(v.z); b.w = f2bf(v.w);
            *(ushort4*)&hb[row * BSTRIDE + c4 * 4] = b;
        }
    }
    __syncthreads();

    int w = t >> 6, lane = t & 63;
    int quad = lane >> 4, m = lane & 15;
    int arow = w * 16 + m;
    short8 a0 = *(const short8*)&hb[arow * BSTRIDE + quad * 8];
    short8 a1 = *(const short8*)&hb[arow * BSTRIDE + 32 + quad * 8];

    for (int r = r0; r < r1; r++) {
        __syncthreads();
        {
            const float4* Wg = (const float4*)(W + (size_t)r * 4096);
#pragma unroll
            for (int i = 0; i < 4; i++) {
                int idx = t + i * 256;
                int k = idx >> 4, e4 = (idx & 15) * 4;
                float4 v = Wg[idx];
                wt[(e4 + 0) * BSTRIDE + k] = f2bf(v.x);
                wt[(e4 + 1) * BSTRIDE + k] = f2bf(v.y);
                wt[(e4 + 2) * BSTRIDE + k] = f2bf(v.z);
                wt[(e4 + 3) * BSTRIDE + k] = f2bf(v.w);
            }
        }
        __syncthreads();

        size_t outBase = ((size_t)(r - r0) * N + n0 + w * 16) * 64;
#pragma unroll
        for (int c = 0; c < 4; c++) {
            short8 b0 = *(const short8*)&wt[(c * 16 + m) * BSTRIDE + quad * 8];
            short8 b1 = *(const short8*)&wt[(c * 16 + m) * BSTRIDE + 32 + quad * 8];
            float4v acc = {0.f, 0.f, 0.f, 0.f};
            acc = __builtin_amdgcn_mfma_f32_16x16x32_bf16(a0, b0, acc, 0, 0, 0);
            acc = __builtin_amdgcn_mfma_f32_16x16x32_bf16(a1, b1, acc, 0, 0, 0);
#pragma unroll
            for (int reg = 0; reg < 4; reg++) {
                int node = n0 + w * 16 + quad * 4 + reg;
                if (node < N)
                    hWb[outBase + (size_t)(quad * 4 + reg) * 64 + c * 16 + m] = f2bf(acc[reg]);
            }
        }
    }
}

// ====== fused softmax + aggregation, grouped gather + pipelined chunk 0 ======
__global__ __launch_bounds__(256) void aggsoft_kernel(
        const int* __restrict__ rowptr, const unsigned* __restrict__ packed,
        const float* __restrict__ attS, const float* __restrict__ attD,
        const unsigned short* __restrict__ hWb, float* __restrict__ agg,
        int n, int N, int R, int r0, int r1, int last) {
    int g = blockIdx.x * blockDim.x + threadIdx.x;
    int wv = g >> 6, lane = g & 63;
    if (wv >= n) return;
    int start = rowptr[wv], end = rowptr[wv + 1];
    int deg = end - start;
    int egrp = lane >> 3, dgrp = lane & 7;

    float acc8[8] = {0.f, 0.f, 0.f, 0.f, 0.f, 0.f, 0.f, 0.f};
    if (r0 != 0) {
#pragma unroll
        for (int j = 0; j < 8; j += 4) {
            float4 v = *(const float4*)&agg[(size_t)wv * 64 + dgrp * 8 + j];
            acc8[j] = v.x; acc8[j + 1] = v.y; acc8[j + 2] = v.z; acc8[j + 3] = v.w;
        }
    }

    if (deg > 0 && deg <= 64) {
        int i = start + lane;
        bool act = i < end;
        unsigned p = act ? packed[i] : 0u;
        int r = p >> 24; unsigned s = p & 0xFFFFFFu;

        // --- pipelined chunk-0 gather: issue VMEM before softmax ---
        unsigned pp0 = (unsigned)__shfl((int)p, egrp);
        int rr0 = (int)(pp0 >> 24);
        bool g0 = (egrp < deg) && rr0 >= r0 && rr0 < r1;
        ushort8v v0 = {};
        if (g0) {
            unsigned row = (unsigned)((rr0 - r0) * N) + (pp0 & 0xFFFFFFu);
            v0 = *(const ushort8v*)&hWb[((size_t)row << 6) + dgrp * 8];
        }

        // --- softmax (lane = edge), degree-adaptive butterfly ---
        float sc = -INFINITY;
        if (act) {
            sc = attS[(size_t)s * R + r] + attD[(size_t)wv * R + r];
            sc = sc > 0.f ? sc : NEG_SLOPE * sc;
        }
        float m = sc, sum;
        if (deg <= 8) {
            for (int o = 4; o; o >>= 1) m = fmaxf(m, __shfl_xor(m, o));
            float ex = act ? __expf(sc - m) : 0.f;
            sum = ex;
            for (int o = 4; o; o >>= 1) sum += __shfl_xor(sum, o);
            sc = ex;   // reuse as ex
        } else {
            for (int o = 32; o; o >>= 1) m = fmaxf(m, __shfl_xor(m, o));
            float ex = act ? __expf(sc - m) : 0.f;
            sum = ex;
            for (int o = 32; o; o >>= 1) sum += __shfl_xor(sum, o);
            sc = ex;
        }
        float a = sc * __builtin_amdgcn_rcpf(sum + 1e-9f);
        float ag = (act && r >= r0 && r < r1) ? a : 0.f;

        // --- chunk 0 fma (data already in flight) ---
        {
            float aa = __shfl(ag, egrp);
            if (g0 && aa != 0.f) {
#pragma unroll
                for (int j = 0; j < 8; j++) acc8[j] = fmaf(aa, bf2f(v0[j]), acc8[j]);
            }
        }
        // --- remaining chunks ---
        int nchunk = (deg + 7) >> 3;
        for (int c = 1; c < nchunk; c++) {
            int el = c * 8 + egrp;
            float aa = __shfl(ag, el);
            unsigned pp = (unsigned)__shfl((int)p, el);
            if (aa != 0.f) {
                unsigned row = (unsigned)(((pp >> 24) - r0) * (unsigned)N) + (pp & 0xFFFFFFu);
                ushort8v v = *(const ushort8v*)&hWb[((size_t)row << 6) + dgrp * 8];
#pragma unroll
                for (int j = 0; j < 8; j++) acc8[j] = fmaf(aa, bf2f(v[j]), acc8[j]);
            }
        }
#pragma unroll
        for (int msk = 8; msk <= 32; msk <<= 1)
#pragma unroll
            for (int j = 0; j < 8; j++) acc8[j] += __shfl_xor(acc8[j], msk);
    } else if (deg > 64) {
        float m = -INFINITY;
        for (int base = start; base < end; base += 64) {
            int i = base + lane;
            if (i < end) {
                unsigned p = packed[i];
                int r = p >> 24; unsigned s = p & 0xFFFFFFu;
                float sc = attS[(size_t)s * R + r] + attD[(size_t)wv * R + r];
                sc = sc > 0.f ? sc : NEG_SLOPE * sc;
                m = fmaxf(m, sc);
            }
        }
        for (int o = 32; o; o >>= 1) m = fmaxf(m, __shfl_xor(m, o));
        float sum = 0.f;
        for (int base = start; base < end; base += 64) {
            int i = base + lane;
            if (i < end) {
                unsigned p = packed[i];
                int r = p >> 24; unsigned s = p & 0xFFFFFFu;
                float sc = attS[(size_t)s * R + r] + attD[(size_t)wv * R + r];
                sc = sc > 0.f ? sc : NEG_SLOPE * sc;
                sum += __expf(sc - m);
            }
        }
        for (int o = 32; o; o >>= 1) sum += __shfl_xor(sum, o);
        float inv = __builtin_amdgcn_rcpf(sum + 1e-9f);
        int nchunk = (deg + 7) >> 3;
        for (int c = 0; c < nchunk; c++) {
            int el = c * 8 + egrp;
            if (el < deg) {
                unsigned p = packed[start + el];
                int r = p >> 24; unsigned s = p & 0xFFFFFFu;
                if (r >= r0 && r < r1) {
                    float sc = attS[(size_t)s * R + r] + attD[(size_t)wv * R + r];
                    sc = sc > 0.f ? sc : NEG_SLOPE * sc;
                    float aa = __expf(sc - m) * inv;
                    unsigned row = (unsigned)((r - r0) * N) + s;
                    ushort8v v = *(const ushort8v*)&hWb[((size_t)row << 6) + dgrp * 8];
#pragma unroll
                    for (int j = 0; j < 8; j++) acc8[j] = fmaf(aa, bf2f(v[j]), acc8[j]);
                }
            }
        }
#pragma unroll
        for (int msk = 8; msk <= 32; msk <<= 1)
#pragma unroll
            for (int j = 0; j < 8; j++) acc8[j] += __shfl_xor(acc8[j], msk);
    }

    if (last) {
#pragma unroll
        for (int j = 0; j < 8; j++)
            acc8[j] = acc8[j] > 0.f ? acc8[j] : (__expf(acc8[j]) - 1.f);
    }
    if (egrp == 0) {
        float4 v0 = {acc8[0], acc8[1], acc8[2], acc8[3]};
        float4 v1 = {acc8[4], acc8[5], acc8[6], acc8[7]};
        *(float4*)&agg[(size_t)wv * 64 + dgrp * 8] = v0;
        *(float4*)&agg[(size_t)wv * 64 + dgrp * 8 + 4] = v1;
    }
}

// ================= pooling / readout =================
__global__ void seg_sum64_kernel(const float* __restrict__ h, const int* __restrict__ seg,
                                 float* __restrict__ out, int N) {
    int i = blockIdx.x * blockDim.x + threadIdx.x;
    if (i >= N * 64) return;
    int n = i >> 6, d = i & 63;
    atomAddF(&out[seg[n] * 64 + d], h[i]);
}

__global__ void readout_kernel(const float* __restrict__ molr, const float* __restrict__ mol,
                               const int* __restrict__ mol2rxn, float* __restrict__ feat, int M) {
    int i = blockIdx.x * blockDim.x + threadIdx.x;
    if (i >= M * 64) return;
    int m = i >> 6, d = i & 63;
    int b = mol2rxn[m];
    atomAddF(&feat[b * 128 + d], molr[i]);
    atomAddF(&feat[b * 128 + 64 + d], mol[i]);
}

// ================= MLP head: LDS-tiled GEMM =================
#define APAD 36
__global__ __launch_bounds__(256) void fc_gemm_kernel(
        const float* __restrict__ A, const float* __restrict__ B,
        const float* __restrict__ bias, const float* __restrict__ prelu,
        float* __restrict__ C, int M, int N, int K, int mode) {
    __shared__ float Al[64 * APAD];
    __shared__ float Bl[32 * 64];
    int t = threadIdx.x;
    int n0 = blockIdx.x * 64, m0 = blockIdx.y * 64;
    int e4 = (t & 15) * 4;
    int n4 = (t >> 4) * 4;
    float acc[4][4] = {};

    for (int k0 = 0; k0 < K; k0 += 32) {
        {
            const float4* Ag = (const float4*)A;
#pragma unroll
            for (int i = 0; i < 2; i++) {
                int idx = t + i * 256;
                int row = idx >> 3, c4 = idx & 7;
                float4 v = Ag[(size_t)(m0 + row) * (K >> 2) + (k0 >> 2) + c4];
                float* p = &Al[row * APAD + c4 * 4];
                p[0] = v.x; p[1] = v.y; p[2] = v.z; p[3] = v.w;
            }
        }
        {
#pragma unroll
            for (int i = 0; i < 2; i++) {
                int idx = t + i * 256;
                int kk = idx >> 4, c4 = (idx & 15) * 4;
                int col = n0 + c4;
                float4 v;
                const float* Brow = B + (size_t)(k0 + kk) * N;
                if (col + 3 < N) v = *(const float4*)&Brow[col];
                else {
                    v.x = (col + 0 < N) ? Brow[col + 0] : 0.f;
                    v.y = (col + 1 < N) ? Brow[col + 1] : 0.f;
                    v.z = (col + 2 < N) ? Brow[col + 2] : 0.f;
                    v.w = 0.f;
                }
                *(float4*)&Bl[kk * 64 + c4] = v;
            }
        }
        __syncthreads();
        for (int d = 0; d < 32; d += 4) {
            float4 wv[4], hv[4];
#pragma unroll
            for (int dd = 0; dd < 4; dd++) wv[dd] = *(const float4*)&Bl[(d + dd) * 64 + e4];
#pragma unroll
            for (int i = 0; i < 4; i++) hv[i] = *(const float4*)&Al[(n4 + i) * APAD + d];
#pragma unroll
            for (int i = 0; i < 4; i++) {
                const float hvv[4] = {hv[i].x, hv[i].y, hv[i].z, hv[i].w};
#pragma unroll
                for (int dd = 0; dd < 4; dd++) {
                    const float* wp = (const float*)&wv[dd];
#pragma unroll
                    for (int j = 0; j < 4; j++) acc[i][j] = fmaf(hvv[dd], wp[j], acc[i][j]);
                }
            }
        }
        __syncthreads();
    }

    float p = mode ? *prelu : 0.f;
#pragma unroll
    for (int i = 0; i < 4; i++) {
        int row = m0 + n4 + i;
#pragma unroll
        for (int j = 0; j < 4; j++) {
            int col = n0 + e4 + j;
            if (col < N) {
                float v = acc[i][j] + bias[col];
                if (mode) v = v > 0.f ? v : p * v;
                C[(size_t)row * N + col] = v;
            }
        }
    }
}

// ================= launch =================
extern "C" void kernel_launch(void* const* d_in, const int* in_sizes, int n_in,
                              void* d_out, int out_size, void* d_ws, size_t ws_size,
                              hipStream_t stream) {
    const float* node_feats = (const float*)d_in[0];
    const int*   edge_src   = (const int*)d_in[1];
    const int*   edge_dst   = (const int*)d_in[2];
    const int*   edge_rel   = (const int*)d_in[3];
    const int*   node2mol   = (const int*)d_in[4];
    const int*   rxn_src    = (const int*)d_in[5];
    const int*   rxn_dst    = (const int*)d_in[6];
    const int*   rxn_rel    = (const int*)d_in[7];
    const int*   mol2rxn    = (const int*)d_in[8];
    const float* W1     = (const float*)d_in[9];
    const float* a_src1 = (const float*)d_in[10];
    const float* a_dst1 = (const float*)d_in[11];
    const float* W2     = (const float*)d_in[12];
    const float* a_src2 = (const float*)d_in[13];
    const float* a_dst2 = (const float*)d_in[14];
    const float* Wr     = (const float*)d_in[15];
    const float* a_srcr = (const float*)d_in[16];
    const float* a_dstr = (const float*)d_in[17];
    const float* w_fc1  = (const float*)d_in[18];
    const float* b_fc1  = (const float*)d_in[19];
    const float* prelu1 = (const float*)d_in[20];
    const float* w_fc2  = (const float*)d_in[21];
    const float* b_fc2  = (const float*)d_in[22];

    const int N = 100000, E = 800000, M = 5000, ER = 40000;

    float* ws = (float*)d_ws;
    float* h1     = ws;                       // 6,400,000
    float* h2     = h1 + 6400000;             // 6,400,000
    float* attS   = h2 + 6400000;             // 800,000
    float* attD   = attS + 800000;            // 800,000
    float* mol    = attD + 800000;            // 320,000
    float* molr   = mol + 320000;             // 320,000
    float* feat   = molr + 320000;            // 131,072
    float* hm     = feat + 131072;            // 524,288
    float* Vsrc   = hm + 524288;              // 512
    float* Vdst   = Vsrc + 512;               // 512
    int* rowptr   = (int*)(Vdst + 512);       // 100,008
    int* cnt      = rowptr + 100008;          // 100,000
    int* incl     = cnt + 100000;             // 100,000
    int* bsum     = incl + 100000;            // 512
    int* cursor   = bsum + 512;               // 100,000
    int* perm     = cursor + 100000;          // 800,000
    unsigned* packed = (unsigned*)(perm + 800000);           // 800,000
    unsigned short* hWb = (unsigned short*)(packed + 800000); // bf16 hW (chunked)

    size_t usedBytes = (size_t)((char*)hWb - (char*)d_ws);
    size_t availUshorts = (ws_size > usedBytes) ? (ws_size - usedBytes) / 2 : 0;

    auto buildCSR = [&](const int* dstArr, const int* srcArr, const int* relArr, int n, int e) {
        hipMemsetAsync(cnt, 0, (size_t)n * sizeof(int), stream);
        hist_kernel<<<dim3((e + 255) / 256), 256, 0, stream>>>(dstArr, cnt, e);
        int nb = (n + 255) / 256;
        scan1_kernel<<<dim3(nb), 256, 0, stream>>>(cnt, incl, bsum, n);
        scan2_kernel<<<dim3(1), 512, 0, stream>>>(bsum, nb);
        scan3_kernel<<<dim3((n + 256) / 256), 256, 0, stream>>>(incl, cnt, bsum, rowptr, cursor, n, e);
        scatter_kernel<<<dim3((e + 255) / 256), 256, 0, stream>>>(dstArr, cursor, perm, e);
        pack_kernel<<<dim3((e + 255) / 256), 256, 0, stream>>>(perm, relArr, srcArr, packed, e);
    };

    auto rgat = [&](const float* hin, int n,
                    const float* W, const float* as, const float* ad,
                    float* agg, int R) {
        compute_v_kernel<<<dim3((R * 64 + 63) / 64), 64, 0, stream>>>(W, as, ad, Vsrc, Vdst, R);
        att_gemm_kernel<<<dim3((n + 63) / 64), 256, 0, stream>>>(hin, Vsrc, Vdst, attS, attD, n, R);

        size_t perRel = (size_t)n * 64;   // ushorts per relation
        int chunk = (int)(availUshorts / perRel);
        if (chunk < 1) chunk = 1;
        if (chunk > R) chunk = R;
        for (int r0 = 0; r0 < R; r0 += chunk) {
            int r1 = r0 + chunk; if (r1 > R) r1 = R;
            hw_gemm_mfma_kernel<<<dim3((n + 63) / 64), 256, 0, stream>>>(hin, W, hWb, n, r0, r1);
            aggsoft_kernel<<<dim3(((size_t)n * 64 + 255) / 256), 256, 0, stream>>>(
                rowptr, packed, attS, attD, hWb, agg, n, n, R, r0, r1, r1 == R ? 1 : 0);
        }
    };

    // ---- atom graph CSR (shared by both atom layers) ----
    buildCSR(edge_dst, edge_src, edge_rel, N, E);
    rgat(node_feats, N, W1, a_src1, a_dst1, h1, 8);
    rgat(h1,         N, W2, a_src2, a_dst2, h2, 8);

    // ---- molecule pooling ----
    hipMemsetAsync(mol, 0, (size_t)M * 64 * sizeof(float), stream);
    seg_sum64_kernel<<<dim3(((size_t)N * 64 + 255) / 256), 256, 0, stream>>>(h2, node2mol, mol, N);

    // ---- reaction-graph RGAT ----
    buildCSR(rxn_dst, rxn_src, rxn_rel, M, ER);
    rgat(mol, M, Wr, a_srcr, a_dstr, molr, 4);

    // ---- reaction readout ----
    hipMemsetAsync(feat, 0, (size_t)1024 * 128 * sizeof(float), stream);
    readout_kernel<<<dim3(((size_t)M * 64 + 255) / 256), 256, 0, stream>>>(molr, mol, mol2rxn, feat, M);

    // ---- MLP head: tiled GEMMs ----
    fc_gemm_kernel<<<dim3(8, 16), 256, 0, stream>>>(feat, w_fc1, b_fc1, prelu1, hm, 1024, 512, 128, 1);
    fc_gemm_kernel<<<dim3(11, 16), 256, 0, stream>>>(hm, w_fc2, b_fc2, nullptr, (float*)d_out, 1024, 703, 512, 0);
}

// Round 13
// 508.438 us; speedup vs baseline: 1.5215x; 1.1108x over previous
//
#include <hip/hip_runtime.h>
#include <math.h>

#define NEG_SLOPE 0.2f

typedef __attribute__((ext_vector_type(8))) short short8;
typedef __attribute__((ext_vector_type(8))) unsigned short ushort8v;
typedef __attribute__((ext_vector_type(4))) float float4v;

__device__ __forceinline__ void atomAddF(float* p, float v) {
    unsafeAtomicAdd(p, v);   // HW global_atomic_add_f32 on gfx950
}
__device__ __forceinline__ unsigned short f2bf(float f) {
    unsigned u = __float_as_uint(f);
    unsigned r = (u + 0x7FFFu + ((u >> 16) & 1u)) >> 16;   // RNE
    return (unsigned short)r;
}
__device__ __forceinline__ float bf2f(unsigned short b) {
    return __uint_as_float((unsigned)b << 16);
}

// ================= CSR build: two-pass LDS-binned sort =================
// Buckets of 512 dst nodes. Edge payload: (dst_local 9b)<<23 | (rel 4b)<<19 | (src 19b).

// per-bucket histogram (LDS-staged)
__global__ void bhist_kernel(const int* __restrict__ dst, int* __restrict__ bcnt, int E) {
    __shared__ int h[256];
    int t = threadIdx.x;
    h[t] = 0;
    __syncthreads();
    for (int e = blockIdx.x * blockDim.x + t; e < E; e += gridDim.x * blockDim.x)
        atomicAdd(&h[dst[e] >> 9], 1);
    __syncthreads();
    if (h[t]) atomicAdd(&bcnt[t], h[t]);
}

// single-block scan of bucket counts -> bbase/bcursor; also rowptr[n]=E
__global__ void bscan_kernel(const int* __restrict__ bcnt, int* __restrict__ bbase,
                             int* __restrict__ bcursor, int NB, int* __restrict__ rowptr,
                             int n, int E) {
    __shared__ int s[256];
    int t = threadIdx.x;
    int v = (t < NB) ? bcnt[t] : 0;
    s[t] = v; __syncthreads();
    for (int o = 1; o < 256; o <<= 1) {
        int u = (t >= o) ? s[t - o] : 0;
        __syncthreads(); s[t] += u; __syncthreads();
    }
    int excl = s[t] - v;
    if (t < NB) { bbase[t] = excl; bcursor[t] = excl; }
    if (t == 0) { bbase[NB] = E; rowptr[n] = E; }
}

// partition edges into buckets; same-block same-bucket edges land contiguously
__global__ __launch_bounds__(256) void bpart_kernel(
        const int* __restrict__ dst, const int* __restrict__ rel, const int* __restrict__ src,
        int* __restrict__ bcursor, unsigned* __restrict__ bpacked, int E, int NB) {
    __shared__ int cntL[256];
    __shared__ int gofsL[256];
    int t = threadIdx.x;
    int e0 = blockIdx.x * 4096;
    cntL[t] = 0;
    __syncthreads();

    unsigned pv[16]; unsigned short li[16]; unsigned char bk[16];
#pragma unroll
    for (int j = 0; j < 16; j++) {
        int e = e0 + t + j * 256;
        bk[j] = 0xFF;
        if (e < E) {
            int d = dst[e];
            int b = d >> 9;
            bk[j] = (unsigned char)b;
            li[j] = (unsigned short)atomicAdd(&cntL[b], 1);
            pv[j] = ((unsigned)(d & 511) << 23) | ((unsigned)rel[e] << 19) | (unsigned)src[e];
        }
    }
    __syncthreads();
    for (int b = t; b < NB; b += 256) {
        int c = cntL[b];
        gofsL[b] = c ? atomicAdd(&bcursor[b], c) : 0;
    }
    __syncthreads();
#pragma unroll
    for (int j = 0; j < 16; j++)
        if (bk[j] != 0xFF) bpacked[gofsL[bk[j]] + li[j]] = pv[j];
}

// within-bucket counting sort in LDS; writes rowptr + final packed[] coalesced
#define BCAP 6400
__global__ __launch_bounds__(256) void bsort_kernel(
        const unsigned* __restrict__ bpacked, const int* __restrict__ bbase,
        int* __restrict__ rowptr, unsigned* __restrict__ packed, int n) {
    __shared__ unsigned ein[BCAP];
    __shared__ unsigned eout[BCAP];
    __shared__ int cnt[512];
    __shared__ int ofs[512];
    __shared__ int s2[256];
    int b = blockIdx.x, t = threadIdx.x;
    int g0 = bbase[b];
    int nb = bbase[b + 1] - g0;
    if (nb > BCAP) nb = BCAP;   // statistically impossible (mean 4081, +36 sigma)

    for (int i = t; i < nb; i += 256) ein[i] = bpacked[g0 + i];
    cnt[t] = 0; cnt[t + 256] = 0;
    __syncthreads();
    for (int i = t; i < nb; i += 256) atomicAdd(&cnt[ein[i] >> 23], 1);
    __syncthreads();
    // scan 512 counters with 256 threads (pairwise + Hillis-Steele)
    int a = cnt[2 * t], c2 = cnt[2 * t + 1];
    s2[t] = a + c2;
    __syncthreads();
    for (int o = 1; o < 256; o <<= 1) {
        int u = (t >= o) ? s2[t - o] : 0;
        __syncthreads(); s2[t] += u; __syncthreads();
    }
    int excl = s2[t] - (a + c2);
    ofs[2 * t] = excl; ofs[2 * t + 1] = excl + a;
    __syncthreads();
    // rowptr (coalesced)
    int d0 = b * 512;
    for (int j = t; j < 512; j += 256) {
        int gd = d0 + j;
        if (gd < n) rowptr[gd] = g0 + ofs[j];
    }
    // cursors (reuse cnt)
    cnt[t] = ofs[t]; cnt[t + 256] = ofs[t + 256];
    __syncthreads();
    // LDS scatter to CSR order, converting payload to (rel<<24)|src
    for (int i = t; i < nb; i += 256) {
        unsigned v = ein[i];
        int pos = atomicAdd(&cnt[v >> 23], 1);
        eout[pos] = (((v >> 19) & 0xFu) << 24) | (v & 0x7FFFFu);
    }
    __syncthreads();
    for (int i = t; i < nb; i += 256) packed[g0 + i] = eout[i];
}

// ================= RGAT =================
__global__ void compute_v_kernel(const float* __restrict__ W,
                                 const float* __restrict__ a_src,
                                 const float* __restrict__ a_dst,
                                 float* __restrict__ Vsrc, float* __restrict__ Vdst,
                                 int R) {
    int idx = blockIdx.x * blockDim.x + threadIdx.x;   // r*64+d
    if (idx >= R * 64) return;
    int r = idx >> 6;
    const float* Wr = W + idx * 64;
    const float* as = a_src + r * 64;
    const float* ad = a_dst + r * 64;
    float s = 0.f, t = 0.f;
    for (int e = 0; e < 64; e++) { float w = Wr[e]; s = fmaf(w, as[e], s); t = fmaf(w, ad[e], t); }
    Vsrc[idx] = s; Vdst[idx] = t;
}

// attS[n*R+r] = h[n,:] . Vsrc[r,:]  -- skinny GEMM, 64-node LDS tile (fp32)
#define HPAD 68
__global__ __launch_bounds__(256) void att_gemm_kernel(
        const float* __restrict__ h,
        const float* __restrict__ Vsrc, const float* __restrict__ Vdst,
        float* __restrict__ attS, float* __restrict__ attD,
        int N, int R) {
    __shared__ float hl[64 * HPAD];
    __shared__ float Vs[8 * HPAD];
    __shared__ float Vd[8 * HPAD];
    int t = threadIdx.x;
    int n0 = blockIdx.x * 64;

    {
        const float4* hg = (const float4*)h;
#pragma unroll
        for (int i = 0; i < 4; i++) {
            int idx = t + i * 256;
            int row = idx >> 4, col4 = idx & 15;
            int node = n0 + row;
            float4 v = (node < N) ? hg[(size_t)node * 16 + col4] : float4{0.f, 0.f, 0.f, 0.f};
            *(float4*)&hl[row * HPAD + col4 * 4] = v;
        }
    }
    for (int i = t; i < R * 64; i += 256) {
        int r = i >> 6, d = i & 63;
        Vs[r * HPAD + d] = Vsrc[i];
        Vd[r * HPAD + d] = Vdst[i];
    }
    __syncthreads();

    for (int p = t; p < 64 * R; p += 256) {
        int node = p / R, r = p - node * R;
        const float4* hp = (const float4*)&hl[node * HPAD];
        const float4* sp = (const float4*)&Vs[r * HPAD];
        const float4* dp = (const float4*)&Vd[r * HPAD];
        float s = 0.f, dd = 0.f;
#pragma unroll
        for (int d4 = 0; d4 < 16; d4++) {
            float4 hv = hp[d4], sv = sp[d4], dv = dp[d4];
            s  = fmaf(hv.x, sv.x, s);  s  = fmaf(hv.y, sv.y, s);
            s  = fmaf(hv.z, sv.z, s);  s  = fmaf(hv.w, sv.w, s);
            dd = fmaf(hv.x, dv.x, dd); dd = fmaf(hv.y, dv.y, dd);
            dd = fmaf(hv.z, dv.z, dd); dd = fmaf(hv.w, dv.w, dd);
        }
        int gn = n0 + node;
        if (gn < N) { attS[(size_t)gn * R + r] = s; attD[(size_t)gn * R + r] = dd; }
    }
}

// hW[rl,n,e] via bf16 MFMA; h tile staged+converted ONCE, loop relations.
#define BSTRIDE 72
__global__ __launch_bounds__(256) void hw_gemm_mfma_kernel(
        const float* __restrict__ h, const float* __restrict__ W,
        unsigned short* __restrict__ hWb, int N, int r0, int r1) {
    __shared__ unsigned short hb[64 * BSTRIDE];
    __shared__ unsigned short wt[64 * BSTRIDE];
    int t = threadIdx.x;
    int n0 = blockIdx.x * 64;

    {
        const float4* hg = (const float4*)h;
#pragma unroll
        for (int i = 0; i < 4; i++) {
            int idx = t + i * 256;
            int row = idx >> 4, c4 = idx & 15;
            int node = n0 + row;
            float4 v = (node < N) ? hg[(size_t)node * 16 + c4] : float4{0.f, 0.f, 0.f, 0.f};
            ushort4 b;
            b.x = f2bf(v.x); b.y = f2bf(v.y); b.z = f2bf(v.z); b.w = f2bf(v.w);
            *(ushort4*)&hb[row * BSTRIDE + c4 * 4] = b;
        }
    }
    __syncthreads();

    int w = t >> 6, lane = t & 63;
    int quad = lane >> 4, m = lane & 15;
    int arow = w * 16 + m;
    short8 a0 = *(const short8*)&hb[arow * BSTRIDE + quad * 8];
    short8 a1 = *(const short8*)&hb[arow * BSTRIDE + 32 + quad * 8];

    for (int r = r0; r < r1; r++) {
        __syncthreads();
        {
            const float4* Wg = (const float4*)(W + (size_t)r * 4096);
#pragma unroll
            for (int i = 0; i < 4; i++) {
                int idx = t + i * 256;
                int k = idx >> 4, e4 = (idx & 15) * 4;
                float4 v = Wg[idx];
                wt[(e4 + 0) * BSTRIDE + k] = f2bf(v.x);
                wt[(e4 + 1) * BSTRIDE + k] = f2bf(v.y);
                wt[(e4 + 2) * BSTRIDE + k] = f2bf(v.z);
                wt[(e4 + 3) * BSTRIDE + k] = f2bf(v.w);
            }
        }
        __syncthreads();

        size_t outBase = ((size_t)(r - r0) * N + n0 + w * 16) * 64;
#pragma unroll
        for (int c = 0; c < 4; c++) {
            short8 b0 = *(const short8*)&wt[(c * 16 + m) * BSTRIDE + quad * 8];
            short8 b1 = *(const short8*)&wt[(c * 16 + m) * BSTRIDE + 32 + quad * 8];
            float4v acc = {0.f, 0.f, 0.f, 0.f};
            acc = __builtin_amdgcn_mfma_f32_16x16x32_bf16(a0, b0, acc, 0, 0, 0);
            acc = __builtin_amdgcn_mfma_f32_16x16x32_bf16(a1, b1, acc, 0, 0, 0);
#pragma unroll
            for (int reg = 0; reg < 4; reg++) {
                int node = n0 + w * 16 + quad * 4 + reg;
                if (node < N)
                    hWb[outBase + (size_t)(quad * 4 + reg) * 64 + c * 16 + m] = f2bf(acc[reg]);
            }
        }
    }
}

// ====== fused softmax + aggregation, grouped gather + pipelined chunk 0 ======
__global__ __launch_bounds__(256) void aggsoft_kernel(
        const int* __restrict__ rowptr, const unsigned* __restrict__ packed,
        const float* __restrict__ attS, const float* __restrict__ attD,
        const unsigned short* __restrict__ hWb, float* __restrict__ agg,
        int n, int N, int R, int r0, int r1, int last) {
    int g = blockIdx.x * blockDim.x + threadIdx.x;
    int wv = g >> 6, lane = g & 63;
    if (wv >= n) return;
    int start = rowptr[wv], end = rowptr[wv + 1];
    int deg = end - start;
    int egrp = lane >> 3, dgrp = lane & 7;

    float acc8[8] = {0.f, 0.f, 0.f, 0.f, 0.f, 0.f, 0.f, 0.f};
    if (r0 != 0) {
#pragma unroll
        for (int j = 0; j < 8; j += 4) {
            float4 v = *(const float4*)&agg[(size_t)wv * 64 + dgrp * 8 + j];
            acc8[j] = v.x; acc8[j + 1] = v.y; acc8[j + 2] = v.z; acc8[j + 3] = v.w;
        }
    }

    if (deg > 0 && deg <= 64) {
        int i = start + lane;
        bool act = i < end;
        unsigned p = act ? packed[i] : 0u;
        int r = p >> 24; unsigned s = p & 0xFFFFFFu;

        // pipelined chunk-0 gather
        unsigned pp0 = (unsigned)__shfl((int)p, egrp);
        int rr0 = (int)(pp0 >> 24);
        bool g0 = (egrp < deg) && rr0 >= r0 && rr0 < r1;
        ushort8v v0 = {};
        if (g0) {
            unsigned row = (unsigned)((rr0 - r0) * N) + (pp0 & 0xFFFFFFu);
            v0 = *(const ushort8v*)&hWb[((size_t)row << 6) + dgrp * 8];
        }

        float sc = -INFINITY;
        if (act) {
            sc = attS[(size_t)s * R + r] + attD[(size_t)wv * R + r];
            sc = sc > 0.f ? sc : NEG_SLOPE * sc;
        }
        float m = sc, sum;
        if (deg <= 8) {
            for (int o = 4; o; o >>= 1) m = fmaxf(m, __shfl_xor(m, o));
            float ex = act ? __expf(sc - m) : 0.f;
            sum = ex;
            for (int o = 4; o; o >>= 1) sum += __shfl_xor(sum, o);
            sc = ex;
        } else {
            for (int o = 32; o; o >>= 1) m = fmaxf(m, __shfl_xor(m, o));
            float ex = act ? __expf(sc - m) : 0.f;
            sum = ex;
            for (int o = 32; o; o >>= 1) sum += __shfl_xor(sum, o);
            sc = ex;
        }
        float a = sc * __builtin_amdgcn_rcpf(sum + 1e-9f);
        float ag = (act && r >= r0 && r < r1) ? a : 0.f;

        {
            float aa = __shfl(ag, egrp);
            if (g0 && aa != 0.f) {
#pragma unroll
                for (int j = 0; j < 8; j++) acc8[j] = fmaf(aa, bf2f(v0[j]), acc8[j]);
            }
        }
        int nchunk = (deg + 7) >> 3;
        for (int c = 1; c < nchunk; c++) {
            int el = c * 8 + egrp;
            float aa = __shfl(ag, el);
            unsigned pp = (unsigned)__shfl((int)p, el);
            if (aa != 0.f) {
                unsigned row = (unsigned)(((pp >> 24) - r0) * (unsigned)N) + (pp & 0xFFFFFFu);
                ushort8v v = *(const ushort8v*)&hWb[((size_t)row << 6) + dgrp * 8];
#pragma unroll
                for (int j = 0; j < 8; j++) acc8[j] = fmaf(aa, bf2f(v[j]), acc8[j]);
            }
        }
#pragma unroll
        for (int msk = 8; msk <= 32; msk <<= 1)
#pragma unroll
            for (int j = 0; j < 8; j++) acc8[j] += __shfl_xor(acc8[j], msk);
    } else if (deg > 64) {
        float m = -INFINITY;
        for (int base = start; base < end; base += 64) {
            int i = base + lane;
            if (i < end) {
                unsigned p = packed[i];
                int r = p >> 24; unsigned s = p & 0xFFFFFFu;
                float sc = attS[(size_t)s * R + r] + attD[(size_t)wv * R + r];
                sc = sc > 0.f ? sc : NEG_SLOPE * sc;
                m = fmaxf(m, sc);
            }
        }
        for (int o = 32; o; o >>= 1) m = fmaxf(m, __shfl_xor(m, o));
        float sum = 0.f;
        for (int base = start; base < end; base += 64) {
            int i = base + lane;
            if (i < end) {
                unsigned p = packed[i];
                int r = p >> 24; unsigned s = p & 0xFFFFFFu;
                float sc = attS[(size_t)s * R + r] + attD[(size_t)wv * R + r];
                sc = sc > 0.f ? sc : NEG_SLOPE * sc;
                sum += __expf(sc - m);
            }
        }
        for (int o = 32; o; o >>= 1) sum += __shfl_xor(sum, o);
        float inv = __builtin_amdgcn_rcpf(sum + 1e-9f);
        int nchunk = (deg + 7) >> 3;
        for (int c = 0; c < nchunk; c++) {
            int el = c * 8 + egrp;
            if (el < deg) {
                unsigned p = packed[start + el];
                int r = p >> 24; unsigned s = p & 0xFFFFFFu;
                if (r >= r0 && r < r1) {
                    float sc = attS[(size_t)s * R + r] + attD[(size_t)wv * R + r];
                    sc = sc > 0.f ? sc : NEG_SLOPE * sc;
                    float aa = __expf(sc - m) * inv;
                    unsigned row = (unsigned)((r - r0) * N) + s;
                    ushort8v v = *(const ushort8v*)&hWb[((size_t)row << 6) + dgrp * 8];
#pragma unroll
                    for (int j = 0; j < 8; j++) acc8[j] = fmaf(aa, bf2f(v[j]), acc8[j]);
                }
            }
        }
#pragma unroll
        for (int msk = 8; msk <= 32; msk <<= 1)
#pragma unroll
            for (int j = 0; j < 8; j++) acc8[j] += __shfl_xor(acc8[j], msk);
    }

    if (last) {
#pragma unroll
        for (int j = 0; j < 8; j++)
            acc8[j] = acc8[j] > 0.f ? acc8[j] : (__expf(acc8[j]) - 1.f);
    }
    if (egrp == 0) {
        float4 v0 = {acc8[0], acc8[1], acc8[2], acc8[3]};
        float4 v1 = {acc8[4], acc8[5], acc8[6], acc8[7]};
        *(float4*)&agg[(size_t)wv * 64 + dgrp * 8] = v0;
        *(float4*)&agg[(size_t)wv * 64 + dgrp * 8 + 4] = v1;
    }
}

// ================= pooling / readout =================
__global__ void seg_sum64_kernel(const float* __restrict__ h, const int* __restrict__ seg,
                                 float* __restrict__ out, int N) {
    int i = blockIdx.x * blockDim.x + threadIdx.x;
    if (i >= N * 64) return;
    int n = i >> 6, d = i & 63;
    atomAddF(&out[seg[n] * 64 + d], h[i]);
}

__global__ void readout_kernel(const float* __restrict__ molr, const float* __restrict__ mol,
                               const int* __restrict__ mol2rxn, float* __restrict__ feat, int M) {
    int i = blockIdx.x * blockDim.x + threadIdx.x;
    if (i >= M * 64) return;
    int m = i >> 6, d = i & 63;
    int b = mol2rxn[m];
    atomAddF(&feat[b * 128 + d], molr[i]);
    atomAddF(&feat[b * 128 + 64 + d], mol[i]);
}

// ================= MLP head: LDS-tiled GEMM =================
#define APAD 36
__global__ __launch_bounds__(256) void fc_gemm_kernel(
        const float* __restrict__ A, const float* __restrict__ B,
        const float* __restrict__ bias, const float* __restrict__ prelu,
        float* __restrict__ C, int M, int N, int K, int mode) {
    __shared__ float Al[64 * APAD];
    __shared__ float Bl[32 * 64];
    int t = threadIdx.x;
    int n0 = blockIdx.x * 64, m0 = blockIdx.y * 64;
    int e4 = (t & 15) * 4;
    int n4 = (t >> 4) * 4;
    float acc[4][4] = {};

    for (int k0 = 0; k0 < K; k0 += 32) {
        {
            const float4* Ag = (const float4*)A;
#pragma unroll
            for (int i = 0; i < 2; i++) {
                int idx = t + i * 256;
                int row = idx >> 3, c4 = idx & 7;
                float4 v = Ag[(size_t)(m0 + row) * (K >> 2) + (k0 >> 2) + c4];
                float* p = &Al[row * APAD + c4 * 4];
                p[0] = v.x; p[1] = v.y; p[2] = v.z; p[3] = v.w;
            }
        }
        {
#pragma unroll
            for (int i = 0; i < 2; i++) {
                int idx = t + i * 256;
                int kk = idx >> 4, c4 = (idx & 15) * 4;
                int col = n0 + c4;
                float4 v;
                const float* Brow = B + (size_t)(k0 + kk) * N;
                if (col + 3 < N) v = *(const float4*)&Brow[col];
                else {
                    v.x = (col + 0 < N) ? Brow[col + 0] : 0.f;
                    v.y = (col + 1 < N) ? Brow[col + 1] : 0.f;
                    v.z = (col + 2 < N) ? Brow[col + 2] : 0.f;
                    v.w = 0.f;
                }
                *(float4*)&Bl[kk * 64 + c4] = v;
            }
        }
        __syncthreads();
        for (int d = 0; d < 32; d += 4) {
            float4 wv[4], hv[4];
#pragma unroll
            for (int dd = 0; dd < 4; dd++) wv[dd] = *(const float4*)&Bl[(d + dd) * 64 + e4];
#pragma unroll
            for (int i = 0; i < 4; i++) hv[i] = *(const float4*)&Al[(n4 + i) * APAD + d];
#pragma unroll
            for (int i = 0; i < 4; i++) {
                const float hvv[4] = {hv[i].x, hv[i].y, hv[i].z, hv[i].w};
#pragma unroll
                for (int dd = 0; dd < 4; dd++) {
                    const float* wp = (const float*)&wv[dd];
#pragma unroll
                    for (int j = 0; j < 4; j++) acc[i][j] = fmaf(hvv[dd], wp[j], acc[i][j]);
                }
            }
        }
        __syncthreads();
    }

    float p = mode ? *prelu : 0.f;
#pragma unroll
    for (int i = 0; i < 4; i++) {
        int row = m0 + n4 + i;
#pragma unroll
        for (int j = 0; j < 4; j++) {
            int col = n0 + e4 + j;
            if (col < N) {
                float v = acc[i][j] + bias[col];
                if (mode) v = v > 0.f ? v : p * v;
                C[(size_t)row * N + col] = v;
            }
        }
    }
}

// ================= launch =================
extern "C" void kernel_launch(void* const* d_in, const int* in_sizes, int n_in,
                              void* d_out, int out_size, void* d_ws, size_t ws_size,
                              hipStream_t stream) {
    const float* node_feats = (const float*)d_in[0];
    const int*   edge_src   = (const int*)d_in[1];
    const int*   edge_dst   = (const int*)d_in[2];
    const int*   edge_rel   = (const int*)d_in[3];
    const int*   node2mol   = (const int*)d_in[4];
    const int*   rxn_src    = (const int*)d_in[5];
    const int*   rxn_dst    = (const int*)d_in[6];
    const int*   rxn_rel    = (const int*)d_in[7];
    const int*   mol2rxn    = (const int*)d_in[8];
    const float* W1     = (const float*)d_in[9];
    const float* a_src1 = (const float*)d_in[10];
    const float* a_dst1 = (const float*)d_in[11];
    const float* W2     = (const float*)d_in[12];
    const float* a_src2 = (const float*)d_in[13];
    const float* a_dst2 = (const float*)d_in[14];
    const float* Wr     = (const float*)d_in[15];
    const float* a_srcr = (const float*)d_in[16];
    const float* a_dstr = (const float*)d_in[17];
    const float* w_fc1  = (const float*)d_in[18];
    const float* b_fc1  = (const float*)d_in[19];
    const float* prelu1 = (const float*)d_in[20];
    const float* w_fc2  = (const float*)d_in[21];
    const float* b_fc2  = (const float*)d_in[22];

    const int N = 100000, E = 800000, M = 5000, ER = 40000;

    float* ws = (float*)d_ws;
    float* h1     = ws;                       // 6,400,000
    float* h2     = h1 + 6400000;             // 6,400,000
    float* attS   = h2 + 6400000;             // 800,000
    float* attD   = attS + 800000;            // 800,000
    float* mol    = attD + 800000;            // 320,000
    float* molr   = mol + 320000;             // 320,000
    float* feat   = molr + 320000;            // 131,072
    float* hm     = feat + 131072;            // 524,288
    float* Vsrc   = hm + 524288;              // 512
    float* Vdst   = Vsrc + 512;               // 512
    int* rowptr   = (int*)(Vdst + 512);       // 100,008
    int* bcnt     = rowptr + 100008;          // 256
    int* bbase    = bcnt + 256;               // 260 (NB+1 max 257)
    int* bcursor  = bbase + 260;              // 256
    unsigned* bpacked = (unsigned*)(bcursor + 256);          // 800,000
    unsigned* packed  = bpacked + 800000;                    // 800,000
    unsigned short* hWb = (unsigned short*)(packed + 800000); // bf16 hW (chunked)

    size_t usedBytes = (size_t)((char*)hWb - (char*)d_ws);
    size_t availUshorts = (ws_size > usedBytes) ? (ws_size - usedBytes) / 2 : 0;

    auto buildCSR = [&](const int* dstArr, const int* srcArr, const int* relArr, int n, int e) {
        int NB = (n + 511) / 512;
        hipMemsetAsync(bcnt, 0, (size_t)NB * sizeof(int), stream);
        bhist_kernel<<<dim3(256), 256, 0, stream>>>(dstArr, bcnt, e);
        bscan_kernel<<<dim3(1), 256, 0, stream>>>(bcnt, bbase, bcursor, NB, rowptr, n, e);
        bpart_kernel<<<dim3((e + 4095) / 4096), 256, 0, stream>>>(dstArr, relArr, srcArr, bcursor, bpacked, e, NB);
        bsort_kernel<<<dim3(NB), 256, 0, stream>>>(bpacked, bbase, rowptr, packed, n);
    };

    auto rgat = [&](const float* hin, int n,
                    const float* W, const float* as, const float* ad,
                    float* agg, int R) {
        compute_v_kernel<<<dim3((R * 64 + 63) / 64), 64, 0, stream>>>(W, as, ad, Vsrc, Vdst, R);
        att_gemm_kernel<<<dim3((n + 63) / 64), 256, 0, stream>>>(hin, Vsrc, Vdst, attS, attD, n, R);

        size_t perRel = (size_t)n * 64;   // ushorts per relation
        int chunk = (int)(availUshorts / perRel);
        if (chunk < 1) chunk = 1;
        if (chunk > R) chunk = R;
        for (int r0 = 0; r0 < R; r0 += chunk) {
            int r1 = r0 + chunk; if (r1 > R) r1 = R;
            hw_gemm_mfma_kernel<<<dim3((n + 63) / 64), 256, 0, stream>>>(hin, W, hWb, n, r0, r1);
            aggsoft_kernel<<<dim3(((size_t)n * 64 + 255) / 256), 256, 0, stream>>>(
                rowptr, packed, attS, attD, hWb, agg, n, n, R, r0, r1, r1 == R ? 1 : 0);
        }
    };

    // ---- atom graph CSR (shared by both atom layers) ----
    buildCSR(edge_dst, edge_src, edge_rel, N, E);
    rgat(node_feats, N, W1, a_src1, a_dst1, h1, 8);
    rgat(h1,         N, W2, a_src2, a_dst2, h2, 8);

    // ---- molecule pooling ----
    hipMemsetAsync(mol, 0, (size_t)M * 64 * sizeof(float), stream);
    seg_sum64_kernel<<<dim3(((size_t)N * 64 + 255) / 256), 256, 0, stream>>>(h2, node2mol, mol, N);

    // ---- reaction-graph RGAT ----
    buildCSR(rxn_dst, rxn_src, rxn_rel, M, ER);
    rgat(mol, M, Wr, a_srcr, a_dstr, molr, 4);

    // ---- reaction readout ----
    hipMemsetAsync(feat, 0, (size_t)1024 * 128 * sizeof(float), stream);
    readout_kernel<<<dim3(((size_t)M * 64 + 255) / 256), 256, 0, stream>>>(molr, mol, mol2rxn, feat, M);

    // ---- MLP head: tiled GEMMs ----
    fc_gemm_kernel<<<dim3(8, 16), 256, 0, stream>>>(feat, w_fc1, b_fc1, prelu1, hm, 1024, 512, 128, 1);
    fc_gemm_kernel<<<dim3(11, 16), 256, 0, stream>>>(hm, w_fc2, b_fc2, nullptr, (float*)d_out, 1024, 703, 512, 0);
}